// Round 1
// baseline (1596.218 us; speedup 1.0000x reference)
//
#include <hip/hip_runtime.h>

#define B   32
#define L   1024
#define MN  512
#define SD  256
#define VD  64
#define DM  256
#define D3  192
#define NH  8
#define DK  32
#define RMAX 30
#define NREL 61

// ---------------------------------------------------------------------------
// Generic row-GEMM: Y[row, d] = act( sum_c X[row, c] * W[d, c] )
// COUT fixed at 256 (= blockDim.x). RPB rows per block amortize W traffic.
// ACT: 0 = none, 1 = sigmoid
// ---------------------------------------------------------------------------
template<int CIN, int RPB, int ACT>
__global__ __launch_bounds__(256) void rowgemm_kernel(
    const float* __restrict__ X, const float* __restrict__ W,
    float* __restrict__ Y) {
  const int row0 = blockIdx.x * RPB;
  const int d = threadIdx.x;
  __shared__ float xs[RPB][CIN];
  float* xsf = &xs[0][0];
  for (int i = d * 4; i < RPB * CIN; i += 256 * 4)
    *(float4*)(xsf + i) = *(const float4*)(X + (size_t)row0 * CIN + i);
  __syncthreads();
  float acc[RPB];
#pragma unroll
  for (int r = 0; r < RPB; ++r) acc[r] = 0.f;
  const float* w = W + (size_t)d * CIN;
  for (int c = 0; c < CIN; c += 4) {
    float4 w4 = *(const float4*)(w + c);
#pragma unroll
    for (int r = 0; r < RPB; ++r) {
      float4 x4 = *(const float4*)&xs[r][c];
      acc[r] += x4.x * w4.x + x4.y * w4.y + x4.z * w4.z + x4.w * w4.w;
    }
  }
#pragma unroll
  for (int r = 0; r < RPB; ++r) {
    float o = acc[r];
    if (ACT == 1) o = 1.f / (1.f + __expf(-o));
    Y[(size_t)(row0 + r) * DM + d] = o;
  }
}

// ---------------------------------------------------------------------------
// Multi-scale conv1d (K=3,5,7), 'same' padding, concat on channel -> [.,.,192]
// block = 192 threads: wave 0 -> K=3, wave 1 -> K=5, wave 2 -> K=7 (uniform K
// per wave, no divergence). RPB=8 output positions per block.
// ---------------------------------------------------------------------------
template<int RPB>
__global__ __launch_bounds__(192) void msconv_kernel(
    const float* __restrict__ xv,
    const float* __restrict__ w3, const float* __restrict__ b3,
    const float* __restrict__ w5, const float* __restrict__ b5,
    const float* __restrict__ w7, const float* __restrict__ b7,
    float* __restrict__ xm) {
  const int bb_ = blockIdx.x / (MN / RPB);
  const int s0  = (blockIdx.x % (MN / RPB)) * RPB;
  const int t = threadIdx.x;
  __shared__ float xs[RPB + 6][VD];   // rows s0-3 .. s0+RPB+2
  for (int i = t; i < (RPB + 6) * VD; i += 192) {
    int r = i / VD, c = i % VD;
    int ss = s0 + r - 3;
    xs[r][c] = (ss >= 0 && ss < MN) ? xv[((size_t)bb_ * MN + ss) * VD + c] : 0.f;
  }
  __syncthreads();
  const int scale = t / VD, o = t % VD;
  const float* w; const float* bi; int K, koff;
  if (scale == 0)      { w = w3 + (size_t)o * VD * 3; bi = b3; K = 3; koff = 2; }
  else if (scale == 1) { w = w5 + (size_t)o * VD * 5; bi = b5; K = 5; koff = 1; }
  else                 { w = w7 + (size_t)o * VD * 7; bi = b7; K = 7; koff = 0; }
  float acc[RPB];
#pragma unroll
  for (int r = 0; r < RPB; ++r) acc[r] = bi[o];
  for (int i = 0; i < VD; ++i) {
    for (int k = 0; k < K; ++k) {
      float wv = w[i * K + k];
#pragma unroll
      for (int r = 0; r < RPB; ++r) acc[r] += xs[r + k + koff][i] * wv;
    }
  }
#pragma unroll
  for (int r = 0; r < RPB; ++r)
    xm[((size_t)bb_ * MN + s0 + r) * D3 + scale * VD + o] = acc[r];
}

// ---------------------------------------------------------------------------
// pos_sum[j, d] = sum_i emb[clip(j-i, -R, R) + R, d] via exact clip counts
// ---------------------------------------------------------------------------
__global__ __launch_bounds__(D3) void possum_kernel(
    const float* __restrict__ emb, float* __restrict__ psum) {
  const int j = blockIdx.x, d = threadIdx.x;
  float acc = 0.f;
  for (int r = 0; r < NREL; ++r) {
    int v = r - RMAX;
    int cnt;
    if (r == 0)            cnt = max(0, MN - (j + RMAX));  // j-i <= -R
    else if (r == NREL - 1) cnt = max(0, j - RMAX + 1);    // j-i >=  R
    else                   cnt = (j - v >= 0 && j - v < MN) ? 1 : 0;
    acc += (float)cnt * emb[(size_t)r * D3 + d];
  }
  psum[(size_t)j * D3 + d] = acc;
}

// ---------------------------------------------------------------------------
// rel-pos-enc closed form (elementwise)
// ---------------------------------------------------------------------------
__global__ __launch_bounds__(D3) void pe_kernel(
    const float* __restrict__ xm, const float* __restrict__ psum,
    const float* __restrict__ emb, const float* __restrict__ dww,
    const float* __restrict__ dwb, float* __restrict__ xpe) {
  const int bb_ = blockIdx.x / MN, j = blockIdx.x % MN;
  const int d = threadIdx.x;
  const size_t base = ((size_t)bb_ * MN + j) * D3 + d;
  float xc = xm[base];
  float fC = xc + emb[(size_t)RMAX * D3 + d];
  float fL = (j > 0)      ? xm[base - D3] + emb[(size_t)(RMAX - 1) * D3 + d] : 0.f;
  float fR = (j < MN - 1) ? xm[base + D3] + emb[(size_t)(RMAX + 1) * D3 + d] : 0.f;
  float dc = fL * dww[d * 3 + 0] + fC * dww[d * 3 + 1] + fR * dww[d * 3 + 2] + dwb[d];
  xpe[base] = xc + (psum[(size_t)j * D3 + d] - fC + dc) * (1.f / MN);
}

// ---------------------------------------------------------------------------
// Flash-style attention. Grid = B*NH*(L/512); block = 256 threads.
// Each thread owns rows l0 = lc*512 + tid and l1 = l0 + 256 for head h.
// K/V tiles (128 x 32) staged in LDS; online softmax; acc in registers.
// NOTE: Ob may alias Qb — each thread writes exactly the 32-float chunk it
// alone read at the start, no cross-thread overlap.
// ---------------------------------------------------------------------------
#define TS 128
__global__ __launch_bounds__(256, 2) void attn_kernel(
    const float* Qb, const float* __restrict__ Kb,
    const float* __restrict__ Vb, float* Ob) {
  const int blk = blockIdx.x;
  const int lc = blk & 1;
  const int h  = (blk >> 1) & 7;
  const int bb_ = blk >> 4;
  const int tid = threadIdx.x;
  const int l0 = lc * 512 + tid;
  __shared__ float Kt[TS][DK];
  __shared__ float Vt[TS][DK];
  float q0[DK], q1[DK];
  const float* q0p = Qb + ((size_t)(bb_ * L + l0)) * DM + h * DK;
  const float* q1p = q0p + (size_t)256 * DM;
#pragma unroll
  for (int j = 0; j < DK; j += 4) {
    *(float4*)&q0[j] = *(const float4*)(q0p + j);
    *(float4*)&q1[j] = *(const float4*)(q1p + j);
  }
  float m0 = -1e30f, m1 = -1e30f, ls0 = 0.f, ls1 = 0.f;
  float acc0[DK], acc1[DK];
#pragma unroll
  for (int j = 0; j < DK; ++j) { acc0[j] = 0.f; acc1[j] = 0.f; }
  const float scale = 0.17677669529663687f;  // 1/sqrt(32)

  for (int t0 = 0; t0 < MN; t0 += TS) {
    __syncthreads();
    for (int i = tid * 4; i < TS * DK; i += 256 * 4) {
      int s = i >> 5, j = i & 31;
      const size_t g = ((size_t)(bb_ * MN + t0 + s)) * DM + h * DK + j;
      *(float4*)&Kt[s][j] = *(const float4*)(Kb + g);
      *(float4*)&Vt[s][j] = *(const float4*)(Vb + g);
    }
    __syncthreads();
#pragma unroll 1
    for (int c = 0; c < TS; c += 16) {
      float sc0[16], sc1[16];
      float ml0 = -1e30f, ml1 = -1e30f;
#pragma unroll
      for (int u = 0; u < 16; ++u) {
        int s = c + u;
        float d0 = 0.f, d1 = 0.f;
#pragma unroll
        for (int j = 0; j < DK; j += 4) {
          float4 k4 = *(const float4*)&Kt[s][j];
          d0 += q0[j] * k4.x + q0[j+1] * k4.y + q0[j+2] * k4.z + q0[j+3] * k4.w;
          d1 += q1[j] * k4.x + q1[j+1] * k4.y + q1[j+2] * k4.z + q1[j+3] * k4.w;
        }
        sc0[u] = d0 * scale; sc1[u] = d1 * scale;
        ml0 = fmaxf(ml0, sc0[u]); ml1 = fmaxf(ml1, sc1[u]);
      }
      float mn0 = fmaxf(m0, ml0), mn1 = fmaxf(m1, ml1);
      float cr0 = __expf(m0 - mn0), cr1 = __expf(m1 - mn1);
      ls0 *= cr0; ls1 *= cr1;
#pragma unroll
      for (int j = 0; j < DK; ++j) { acc0[j] *= cr0; acc1[j] *= cr1; }
#pragma unroll
      for (int u = 0; u < 16; ++u) {
        int s = c + u;
        float p0 = __expf(sc0[u] - mn0), p1 = __expf(sc1[u] - mn1);
        ls0 += p0; ls1 += p1;
#pragma unroll
        for (int j = 0; j < DK; j += 4) {
          float4 v4 = *(const float4*)&Vt[s][j];
          acc0[j]   += p0 * v4.x; acc0[j+1] += p0 * v4.y;
          acc0[j+2] += p0 * v4.z; acc0[j+3] += p0 * v4.w;
          acc1[j]   += p1 * v4.x; acc1[j+1] += p1 * v4.y;
          acc1[j+2] += p1 * v4.z; acc1[j+3] += p1 * v4.w;
        }
      }
      m0 = mn0; m1 = mn1;
    }
  }
  float r0 = 1.f / ls0, r1 = 1.f / ls1;
  float* o0 = Ob + ((size_t)(bb_ * L + l0)) * DM + h * DK;
  float* o1 = o0 + (size_t)256 * DM;
#pragma unroll
  for (int j = 0; j < DK; ++j) { o0[j] = acc0[j] * r0; o1[j] = acc1[j] * r1; }
}

// ---------------------------------------------------------------------------
// Final: fc (RPB rows/block) + Gamma-tile gating + residual + LayerNorm
// ---------------------------------------------------------------------------
template<int RPB>
__global__ __launch_bounds__(256) void final_kernel(
    const float* __restrict__ A, const float* __restrict__ fcw,
    const float* __restrict__ fcb, const float* __restrict__ G,
    const float* __restrict__ Xs, const float* __restrict__ lnw,
    const float* __restrict__ lnb, float* __restrict__ out) {
  const int row0 = blockIdx.x * RPB;
  const int d = threadIdx.x;
  __shared__ float xs[RPB][DM];
  float* xsf = &xs[0][0];
  for (int i = d * 4; i < RPB * DM; i += 256 * 4)
    *(float4*)(xsf + i) = *(const float4*)(A + (size_t)row0 * DM + i);
  __syncthreads();
  float acc[RPB];
  const float bv = fcb[d];
#pragma unroll
  for (int r = 0; r < RPB; ++r) acc[r] = bv;
  const float* w = fcw + (size_t)d * DM;
  for (int c = 0; c < DM; c += 4) {
    float4 w4 = *(const float4*)(w + c);
#pragma unroll
    for (int r = 0; r < RPB; ++r) {
      float4 x4 = *(const float4*)&xs[r][c];
      acc[r] += x4.x * w4.x + x4.y * w4.y + x4.z * w4.z + x4.w * w4.w;
    }
  }
  float v[RPB];
#pragma unroll
  for (int r = 0; r < RPB; ++r) {
    int row = row0 + r;
    int bb_ = row >> 10;        // / L
    int l   = row & 1023;
    float g = G[((size_t)bb_ * MN + (l & 511)) * DM + d];
    v[r] = Xs[(size_t)row * SD + d] + g * acc[r];
  }
  __shared__ float p1[RPB][4], p2[RPB][4];
#pragma unroll
  for (int r = 0; r < RPB; ++r) {
    float s1 = v[r], s2 = v[r] * v[r];
    for (int o = 32; o > 0; o >>= 1) {
      s1 += __shfl_down(s1, o);
      s2 += __shfl_down(s2, o);
    }
    if ((d & 63) == 0) { p1[r][d >> 6] = s1; p2[r][d >> 6] = s2; }
  }
  __syncthreads();
#pragma unroll
  for (int r = 0; r < RPB; ++r) {
    float t1 = p1[r][0] + p1[r][1] + p1[r][2] + p1[r][3];
    float t2 = p2[r][0] + p2[r][1] + p2[r][2] + p2[r][3];
    float mu = t1 * (1.f / DM);
    float var = t2 * (1.f / DM) - mu * mu;
    float rs = rsqrtf(var + 1e-5f);
    out[(size_t)(row0 + r) * DM + d] = (v[r] - mu) * rs * lnw[d] + lnb[d];
  }
}

// ---------------------------------------------------------------------------
extern "C" void kernel_launch(void* const* d_in, const int* in_sizes, int n_in,
                              void* d_out, int out_size, void* d_ws, size_t ws_size,
                              hipStream_t stream) {
  const float* x_spatial  = (const float*)d_in[0];
  const float* x_velocity = (const float*)d_in[1];
  const float* Wg   = (const float*)d_in[2];
  const float* w3   = (const float*)d_in[3];
  const float* b3   = (const float*)d_in[4];
  const float* w5   = (const float*)d_in[5];
  const float* b5   = (const float*)d_in[6];
  const float* w7   = (const float*)d_in[7];
  const float* b7   = (const float*)d_in[8];
  const float* remb = (const float*)d_in[9];
  const float* dww  = (const float*)d_in[10];
  const float* dwb  = (const float*)d_in[11];
  const float* Wq   = (const float*)d_in[12];
  const float* Wk   = (const float*)d_in[13];
  const float* Wv   = (const float*)d_in[14];
  const float* fcw  = (const float*)d_in[15];
  const float* fcb  = (const float*)d_in[16];
  const float* lnw  = (const float*)d_in[17];
  const float* lnb  = (const float*)d_in[18];
  float* out = (float*)d_out;

  // workspace layout (floats); total ~27.4M floats = ~110 MB
  float* ws = (float*)d_ws;
  size_t off = 0;
  float* Gamma = ws + off; off += (size_t)B * MN * DM;   // 4.19M
  float* xm    = ws + off; off += (size_t)B * MN * D3;   // 3.15M
  float* psum  = ws + off; off += (size_t)MN * D3;       // 0.10M
  float* xpe   = ws + off; off += (size_t)B * MN * D3;   // 3.15M
  float* Qb    = ws + off; off += (size_t)B * L * DM;    // 8.39M (aliased as attn out)
  float* Kp    = ws + off; off += (size_t)B * MN * DM;   // 4.19M
  float* Vp    = ws + off; off += (size_t)B * MN * DM;   // 4.19M
  float* attn_out = Qb;  // alias — safe: each thread rewrites only its own chunk

  rowgemm_kernel<VD, 8, 1><<<B * MN / 8, 256, 0, stream>>>(x_velocity, Wg, Gamma);
  msconv_kernel<8><<<B * MN / 8, 192, 0, stream>>>(x_velocity, w3, b3, w5, b5, w7, b7, xm);
  possum_kernel<<<MN, D3, 0, stream>>>(remb, psum);
  pe_kernel<<<B * MN, D3, 0, stream>>>(xm, psum, remb, dww, dwb, xpe);
  rowgemm_kernel<SD, 8, 0><<<B * L / 8, 256, 0, stream>>>(x_spatial, Wq, Qb);
  rowgemm_kernel<D3, 8, 0><<<B * MN / 8, 256, 0, stream>>>(xpe, Wk, Kp);
  rowgemm_kernel<D3, 8, 0><<<B * MN / 8, 256, 0, stream>>>(xpe, Wv, Vp);
  attn_kernel<<<B * NH * (L / 512), 256, 0, stream>>>(Qb, Kp, Vp, attn_out);
  final_kernel<8><<<B * L / 8, 256, 0, stream>>>(attn_out, fcw, fcb, Gamma,
                                                 x_spatial, lnw, lnb, out);
}

// Round 2
// 1200.795 us; speedup vs baseline: 1.3293x; 1.3293x over previous
//
#include <hip/hip_runtime.h>

#define B   32
#define L   1024
#define MN  512
#define SD  256
#define VD  64
#define DM  256
#define D3  192
#define NH  8
#define DK  32
#define RMAX 30
#define NREL 61

// ---------------------------------------------------------------------------
// Generic row-GEMM: Y[row, d] = act( sum_c X[row, c] * W[d, c] )
// COUT fixed at 256 (= blockDim.x). RPB rows per block amortize W traffic.
// ACT: 0 = none, 1 = sigmoid
// ---------------------------------------------------------------------------
template<int CIN, int RPB, int ACT>
__global__ __launch_bounds__(256) void rowgemm_kernel(
    const float* __restrict__ X, const float* __restrict__ W,
    float* __restrict__ Y) {
  const int row0 = blockIdx.x * RPB;
  const int d = threadIdx.x;
  __shared__ float xs[RPB][CIN];
  float* xsf = &xs[0][0];
  for (int i = d * 4; i < RPB * CIN; i += 256 * 4)
    *(float4*)(xsf + i) = *(const float4*)(X + (size_t)row0 * CIN + i);
  __syncthreads();
  float acc[RPB];
#pragma unroll
  for (int r = 0; r < RPB; ++r) acc[r] = 0.f;
  const float* w = W + (size_t)d * CIN;
  for (int c = 0; c < CIN; c += 4) {
    float4 w4 = *(const float4*)(w + c);
#pragma unroll
    for (int r = 0; r < RPB; ++r) {
      float4 x4 = *(const float4*)&xs[r][c];
      acc[r] += x4.x * w4.x + x4.y * w4.y + x4.z * w4.z + x4.w * w4.w;
    }
  }
#pragma unroll
  for (int r = 0; r < RPB; ++r) {
    float o = acc[r];
    if (ACT == 1) o = 1.f / (1.f + __expf(-o));
    Y[(size_t)(row0 + r) * DM + d] = o;
  }
}

// ---------------------------------------------------------------------------
// Multi-scale conv1d (K=3,5,7), 'same' padding, concat on channel -> [.,.,192]
// ---------------------------------------------------------------------------
template<int RPB>
__global__ __launch_bounds__(192) void msconv_kernel(
    const float* __restrict__ xv,
    const float* __restrict__ w3, const float* __restrict__ b3,
    const float* __restrict__ w5, const float* __restrict__ b5,
    const float* __restrict__ w7, const float* __restrict__ b7,
    float* __restrict__ xm) {
  const int bb_ = blockIdx.x / (MN / RPB);
  const int s0  = (blockIdx.x % (MN / RPB)) * RPB;
  const int t = threadIdx.x;
  __shared__ float xs[RPB + 6][VD];   // rows s0-3 .. s0+RPB+2
  for (int i = t; i < (RPB + 6) * VD; i += 192) {
    int r = i / VD, c = i % VD;
    int ss = s0 + r - 3;
    xs[r][c] = (ss >= 0 && ss < MN) ? xv[((size_t)bb_ * MN + ss) * VD + c] : 0.f;
  }
  __syncthreads();
  const int scale = t / VD, o = t % VD;
  const float* w; const float* bi; int K, koff;
  if (scale == 0)      { w = w3 + (size_t)o * VD * 3; bi = b3; K = 3; koff = 2; }
  else if (scale == 1) { w = w5 + (size_t)o * VD * 5; bi = b5; K = 5; koff = 1; }
  else                 { w = w7 + (size_t)o * VD * 7; bi = b7; K = 7; koff = 0; }
  float acc[RPB];
#pragma unroll
  for (int r = 0; r < RPB; ++r) acc[r] = bi[o];
  for (int i = 0; i < VD; ++i) {
    for (int k = 0; k < K; ++k) {
      float wv = w[i * K + k];
#pragma unroll
      for (int r = 0; r < RPB; ++r) acc[r] += xs[r + k + koff][i] * wv;
    }
  }
#pragma unroll
  for (int r = 0; r < RPB; ++r)
    xm[((size_t)bb_ * MN + s0 + r) * D3 + scale * VD + o] = acc[r];
}

// ---------------------------------------------------------------------------
// pos_sum[j, d] = sum_i emb[clip(j-i, -R, R) + R, d] via exact clip counts
// ---------------------------------------------------------------------------
__global__ __launch_bounds__(D3) void possum_kernel(
    const float* __restrict__ emb, float* __restrict__ psum) {
  const int j = blockIdx.x, d = threadIdx.x;
  float acc = 0.f;
  for (int r = 0; r < NREL; ++r) {
    int v = r - RMAX;
    int cnt;
    if (r == 0)            cnt = max(0, MN - (j + RMAX));  // j-i <= -R
    else if (r == NREL - 1) cnt = max(0, j - RMAX + 1);    // j-i >=  R
    else                   cnt = (j - v >= 0 && j - v < MN) ? 1 : 0;
    acc += (float)cnt * emb[(size_t)r * D3 + d];
  }
  psum[(size_t)j * D3 + d] = acc;
}

// ---------------------------------------------------------------------------
// rel-pos-enc closed form (elementwise)
// ---------------------------------------------------------------------------
__global__ __launch_bounds__(D3) void pe_kernel(
    const float* __restrict__ xm, const float* __restrict__ psum,
    const float* __restrict__ emb, const float* __restrict__ dww,
    const float* __restrict__ dwb, float* __restrict__ xpe) {
  const int bb_ = blockIdx.x / MN, j = blockIdx.x % MN;
  const int d = threadIdx.x;
  const size_t base = ((size_t)bb_ * MN + j) * D3 + d;
  float xc = xm[base];
  float fC = xc + emb[(size_t)RMAX * D3 + d];
  float fL = (j > 0)      ? xm[base - D3] + emb[(size_t)(RMAX - 1) * D3 + d] : 0.f;
  float fR = (j < MN - 1) ? xm[base + D3] + emb[(size_t)(RMAX + 1) * D3 + d] : 0.f;
  float dc = fL * dww[d * 3 + 0] + fC * dww[d * 3 + 1] + fR * dww[d * 3 + 2] + dwb[d];
  xpe[base] = xc + (psum[(size_t)j * D3 + d] - fC + dc) * (1.f / MN);
}

// ---------------------------------------------------------------------------
// Flash-style attention. Grid = B*NH*(L/512); block = 256 threads.
// Each thread owns rows l0 = lc*512 + tid and l1 = l0 + 256 for head h.
// K/V tiles (128 x 32) in LDS; online softmax; acc in registers.
// launch_bounds(256,1): ~170 VGPRs needed — (256,2) capped at 128 and spilled
// 3.3 GB of scratch traffic to HBM (R1 post-mortem). Chunk=8 trims sc[] regs.
// ---------------------------------------------------------------------------
#define TS 128
#define CH 8
__global__ __launch_bounds__(256, 1) void attn_kernel(
    const float* Qb, const float* __restrict__ Kb,
    const float* __restrict__ Vb, float* Ob) {
  const int blk = blockIdx.x;
  const int lc = blk & 1;
  const int h  = (blk >> 1) & 7;
  const int bb_ = blk >> 4;
  const int tid = threadIdx.x;
  const int l0 = lc * 512 + tid;
  __shared__ float Kt[TS][DK];
  __shared__ float Vt[TS][DK];
  float q0[DK], q1[DK];
  const float* q0p = Qb + ((size_t)(bb_ * L + l0)) * DM + h * DK;
  const float* q1p = q0p + (size_t)256 * DM;
#pragma unroll
  for (int j = 0; j < DK; j += 4) {
    *(float4*)&q0[j] = *(const float4*)(q0p + j);
    *(float4*)&q1[j] = *(const float4*)(q1p + j);
  }
  float m0 = -1e30f, m1 = -1e30f, ls0 = 0.f, ls1 = 0.f;
  float acc0[DK], acc1[DK];
#pragma unroll
  for (int j = 0; j < DK; ++j) { acc0[j] = 0.f; acc1[j] = 0.f; }
  const float scale = 0.17677669529663687f;  // 1/sqrt(32)

  for (int t0 = 0; t0 < MN; t0 += TS) {
    __syncthreads();
    for (int i = tid * 4; i < TS * DK; i += 256 * 4) {
      int s = i >> 5, j = i & 31;
      const size_t g = ((size_t)(bb_ * MN + t0 + s)) * DM + h * DK + j;
      *(float4*)&Kt[s][j] = *(const float4*)(Kb + g);
      *(float4*)&Vt[s][j] = *(const float4*)(Vb + g);
    }
    __syncthreads();
#pragma unroll 1
    for (int c = 0; c < TS; c += CH) {
      float sc0[CH], sc1[CH];
      float ml0 = -1e30f, ml1 = -1e30f;
#pragma unroll
      for (int u = 0; u < CH; ++u) {
        int s = c + u;
        float d0 = 0.f, d1 = 0.f;
#pragma unroll
        for (int j = 0; j < DK; j += 4) {
          float4 k4 = *(const float4*)&Kt[s][j];
          d0 += q0[j] * k4.x + q0[j+1] * k4.y + q0[j+2] * k4.z + q0[j+3] * k4.w;
          d1 += q1[j] * k4.x + q1[j+1] * k4.y + q1[j+2] * k4.z + q1[j+3] * k4.w;
        }
        sc0[u] = d0 * scale; sc1[u] = d1 * scale;
        ml0 = fmaxf(ml0, sc0[u]); ml1 = fmaxf(ml1, sc1[u]);
      }
      float mn0 = fmaxf(m0, ml0), mn1 = fmaxf(m1, ml1);
      float cr0 = __expf(m0 - mn0), cr1 = __expf(m1 - mn1);
      ls0 *= cr0; ls1 *= cr1;
#pragma unroll
      for (int j = 0; j < DK; ++j) { acc0[j] *= cr0; acc1[j] *= cr1; }
#pragma unroll
      for (int u = 0; u < CH; ++u) {
        int s = c + u;
        float p0 = __expf(sc0[u] - mn0), p1 = __expf(sc1[u] - mn1);
        ls0 += p0; ls1 += p1;
#pragma unroll
        for (int j = 0; j < DK; j += 4) {
          float4 v4 = *(const float4*)&Vt[s][j];
          acc0[j]   += p0 * v4.x; acc0[j+1] += p0 * v4.y;
          acc0[j+2] += p0 * v4.z; acc0[j+3] += p0 * v4.w;
          acc1[j]   += p1 * v4.x; acc1[j+1] += p1 * v4.y;
          acc1[j+2] += p1 * v4.z; acc1[j+3] += p1 * v4.w;
        }
      }
      m0 = mn0; m1 = mn1;
    }
  }
  float r0 = 1.f / ls0, r1 = 1.f / ls1;
  float* o0 = Ob + ((size_t)(bb_ * L + l0)) * DM + h * DK;
  float* o1 = o0 + (size_t)256 * DM;
#pragma unroll
  for (int j = 0; j < DK; j += 4) {
    float4 t0v = make_float4(acc0[j] * r0, acc0[j+1] * r0, acc0[j+2] * r0, acc0[j+3] * r0);
    float4 t1v = make_float4(acc1[j] * r1, acc1[j+1] * r1, acc1[j+2] * r1, acc1[j+3] * r1);
    *(float4*)(o0 + j) = t0v;
    *(float4*)(o1 + j) = t1v;
  }
}

// ---------------------------------------------------------------------------
// Final: fc (RPB rows/block) + Gamma-tile gating + residual + LayerNorm
// ---------------------------------------------------------------------------
template<int RPB>
__global__ __launch_bounds__(256) void final_kernel(
    const float* __restrict__ A, const float* __restrict__ fcw,
    const float* __restrict__ fcb, const float* __restrict__ G,
    const float* __restrict__ Xs, const float* __restrict__ lnw,
    const float* __restrict__ lnb, float* __restrict__ out) {
  const int row0 = blockIdx.x * RPB;
  const int d = threadIdx.x;
  __shared__ float xs[RPB][DM];
  float* xsf = &xs[0][0];
  for (int i = d * 4; i < RPB * DM; i += 256 * 4)
    *(float4*)(xsf + i) = *(const float4*)(A + (size_t)row0 * DM + i);
  __syncthreads();
  float acc[RPB];
  const float bv = fcb[d];
#pragma unroll
  for (int r = 0; r < RPB; ++r) acc[r] = bv;
  const float* w = fcw + (size_t)d * DM;
  for (int c = 0; c < DM; c += 4) {
    float4 w4 = *(const float4*)(w + c);
#pragma unroll
    for (int r = 0; r < RPB; ++r) {
      float4 x4 = *(const float4*)&xs[r][c];
      acc[r] += x4.x * w4.x + x4.y * w4.y + x4.z * w4.z + x4.w * w4.w;
    }
  }
  float v[RPB];
#pragma unroll
  for (int r = 0; r < RPB; ++r) {
    int row = row0 + r;
    int bb_ = row >> 10;        // / L
    int l   = row & 1023;
    float g = G[((size_t)bb_ * MN + (l & 511)) * DM + d];
    v[r] = Xs[(size_t)row * SD + d] + g * acc[r];
  }
  __shared__ float p1[RPB][4], p2[RPB][4];
#pragma unroll
  for (int r = 0; r < RPB; ++r) {
    float s1 = v[r], s2 = v[r] * v[r];
    for (int o = 32; o > 0; o >>= 1) {
      s1 += __shfl_down(s1, o);
      s2 += __shfl_down(s2, o);
    }
    if ((d & 63) == 0) { p1[r][d >> 6] = s1; p2[r][d >> 6] = s2; }
  }
  __syncthreads();
#pragma unroll
  for (int r = 0; r < RPB; ++r) {
    float t1 = p1[r][0] + p1[r][1] + p1[r][2] + p1[r][3];
    float t2 = p2[r][0] + p2[r][1] + p2[r][2] + p2[r][3];
    float mu = t1 * (1.f / DM);
    float var = t2 * (1.f / DM) - mu * mu;
    float rs = rsqrtf(var + 1e-5f);
    out[(size_t)(row0 + r) * DM + d] = (v[r] - mu) * rs * lnw[d] + lnb[d];
  }
}

// ---------------------------------------------------------------------------
extern "C" void kernel_launch(void* const* d_in, const int* in_sizes, int n_in,
                              void* d_out, int out_size, void* d_ws, size_t ws_size,
                              hipStream_t stream) {
  const float* x_spatial  = (const float*)d_in[0];
  const float* x_velocity = (const float*)d_in[1];
  const float* Wg   = (const float*)d_in[2];
  const float* w3   = (const float*)d_in[3];
  const float* b3   = (const float*)d_in[4];
  const float* w5   = (const float*)d_in[5];
  const float* b5   = (const float*)d_in[6];
  const float* w7   = (const float*)d_in[7];
  const float* b7   = (const float*)d_in[8];
  const float* remb = (const float*)d_in[9];
  const float* dww  = (const float*)d_in[10];
  const float* dwb  = (const float*)d_in[11];
  const float* Wq   = (const float*)d_in[12];
  const float* Wk   = (const float*)d_in[13];
  const float* Wv   = (const float*)d_in[14];
  const float* fcw  = (const float*)d_in[15];
  const float* fcb  = (const float*)d_in[16];
  const float* lnw  = (const float*)d_in[17];
  const float* lnb  = (const float*)d_in[18];
  float* out = (float*)d_out;

  float* ws = (float*)d_ws;
  size_t off = 0;
  float* Gamma = ws + off; off += (size_t)B * MN * DM;
  float* xm    = ws + off; off += (size_t)B * MN * D3;
  float* psum  = ws + off; off += (size_t)MN * D3;
  float* xpe   = ws + off; off += (size_t)B * MN * D3;
  float* Qb    = ws + off; off += (size_t)B * L * DM;
  float* Kp    = ws + off; off += (size_t)B * MN * DM;
  float* Vp    = ws + off; off += (size_t)B * MN * DM;
  float* attn_out = Qb;  // alias — safe: each thread rewrites only its own chunk

  rowgemm_kernel<VD, 8, 1><<<B * MN / 8, 256, 0, stream>>>(x_velocity, Wg, Gamma);
  msconv_kernel<8><<<B * MN / 8, 192, 0, stream>>>(x_velocity, w3, b3, w5, b5, w7, b7, xm);
  possum_kernel<<<MN, D3, 0, stream>>>(remb, psum);
  pe_kernel<<<B * MN, D3, 0, stream>>>(xm, psum, remb, dww, dwb, xpe);
  rowgemm_kernel<SD, 8, 0><<<B * L / 8, 256, 0, stream>>>(x_spatial, Wq, Qb);
  rowgemm_kernel<D3, 8, 0><<<B * MN / 8, 256, 0, stream>>>(xpe, Wk, Kp);
  rowgemm_kernel<D3, 8, 0><<<B * MN / 8, 256, 0, stream>>>(xpe, Wv, Vp);
  attn_kernel<<<B * NH * (L / 512), 256, 0, stream>>>(Qb, Kp, Vp, attn_out);
  final_kernel<8><<<B * L / 8, 256, 0, stream>>>(attn_out, fcw, fcb, Gamma,
                                                 x_spatial, lnw, lnb, out);
}

// Round 3
// 869.586 us; speedup vs baseline: 1.8356x; 1.3809x over previous
//
#include <hip/hip_runtime.h>

#define B   32
#define L   1024
#define MN  512
#define SD  256
#define VD  64
#define DM  256
#define D3  192
#define NH  8
#define DK  32
#define RMAX 30
#define NREL 61

typedef __attribute__((ext_vector_type(8))) __bf16 bf16x8;
typedef __attribute__((ext_vector_type(4))) float  f32x4;

static __device__ __forceinline__ ushort f2bf(float f) {
  unsigned u = __float_as_uint(f);
  unsigned r = (u + 0x7FFFu + ((u >> 16) & 1u)) >> 16;
  return (ushort)r;
}
static __device__ __forceinline__ bf16x8 ldbf8(const ushort* p) {
  return __builtin_bit_cast(bf16x8, *(const uint4*)p);
}

// ---------------------------------------------------------------------------
// Row-GEMM: Y[row, d] = act( sum_c X[row, c] * W[d, c] ), 256 out channels.
// OMODE: 0 = f32 [row][DM]; 1 = bf16 [row][DM]; 2 = bf16 V^T [b][h][dk][s]
// ACT: 0 = none, 1 = sigmoid
// ---------------------------------------------------------------------------
template<int CIN, int RPB, int ACT, int OMODE>
__global__ __launch_bounds__(256) void rowgemm_kernel(
    const float* __restrict__ X, const float* __restrict__ W, void* Yv) {
  const int row0 = blockIdx.x * RPB;
  const int d = threadIdx.x;
  __shared__ float xs[RPB][CIN];
  float* xsf = &xs[0][0];
  for (int i = d * 4; i < RPB * CIN; i += 256 * 4)
    *(float4*)(xsf + i) = *(const float4*)(X + (size_t)row0 * CIN + i);
  __syncthreads();
  float acc[RPB];
#pragma unroll
  for (int r = 0; r < RPB; ++r) acc[r] = 0.f;
  const float* w = W + (size_t)d * CIN;
  for (int c = 0; c < CIN; c += 4) {
    float4 w4 = *(const float4*)(w + c);
#pragma unroll
    for (int r = 0; r < RPB; ++r) {
      float4 x4 = *(const float4*)&xs[r][c];
      acc[r] += x4.x * w4.x + x4.y * w4.y + x4.z * w4.z + x4.w * w4.w;
    }
  }
#pragma unroll
  for (int r = 0; r < RPB; ++r) {
    float o = acc[r];
    if (ACT == 1) o = 1.f / (1.f + __expf(-o));
    int row = row0 + r;
    if (OMODE == 0) {
      ((float*)Yv)[(size_t)row * DM + d] = o;
    } else if (OMODE == 1) {
      ((ushort*)Yv)[(size_t)row * DM + d] = f2bf(o);
    } else {
      int b_ = row >> 9, s = row & 511;
      ((ushort*)Yv)[((size_t)((b_ * NH + (d >> 5)) * DK + (d & 31))) * MN + s] = f2bf(o);
    }
  }
}

// ---------------------------------------------------------------------------
// Multi-scale conv1d (K=3,5,7), 'same' padding, concat -> [.,.,192]
// ---------------------------------------------------------------------------
template<int RPB>
__global__ __launch_bounds__(192) void msconv_kernel(
    const float* __restrict__ xv,
    const float* __restrict__ w3, const float* __restrict__ b3,
    const float* __restrict__ w5, const float* __restrict__ b5,
    const float* __restrict__ w7, const float* __restrict__ b7,
    float* __restrict__ xm) {
  const int bb_ = blockIdx.x / (MN / RPB);
  const int s0  = (blockIdx.x % (MN / RPB)) * RPB;
  const int t = threadIdx.x;
  __shared__ float xs[RPB + 6][VD];
  for (int i = t; i < (RPB + 6) * VD; i += 192) {
    int r = i / VD, c = i % VD;
    int ss = s0 + r - 3;
    xs[r][c] = (ss >= 0 && ss < MN) ? xv[((size_t)bb_ * MN + ss) * VD + c] : 0.f;
  }
  __syncthreads();
  const int scale = t / VD, o = t % VD;
  const float* w; const float* bi; int K, koff;
  if (scale == 0)      { w = w3 + (size_t)o * VD * 3; bi = b3; K = 3; koff = 2; }
  else if (scale == 1) { w = w5 + (size_t)o * VD * 5; bi = b5; K = 5; koff = 1; }
  else                 { w = w7 + (size_t)o * VD * 7; bi = b7; K = 7; koff = 0; }
  float acc[RPB];
#pragma unroll
  for (int r = 0; r < RPB; ++r) acc[r] = bi[o];
  for (int i = 0; i < VD; ++i) {
    for (int k = 0; k < K; ++k) {
      float wv = w[i * K + k];
#pragma unroll
      for (int r = 0; r < RPB; ++r) acc[r] += xs[r + k + koff][i] * wv;
    }
  }
#pragma unroll
  for (int r = 0; r < RPB; ++r)
    xm[((size_t)bb_ * MN + s0 + r) * D3 + scale * VD + o] = acc[r];
}

// ---------------------------------------------------------------------------
// pos_sum[j, d] = sum_i emb[clip(j-i, -R, R) + R, d]
// ---------------------------------------------------------------------------
__global__ __launch_bounds__(D3) void possum_kernel(
    const float* __restrict__ emb, float* __restrict__ psum) {
  const int j = blockIdx.x, d = threadIdx.x;
  float acc = 0.f;
  for (int r = 0; r < NREL; ++r) {
    int v = r - RMAX;
    int cnt;
    if (r == 0)             cnt = max(0, MN - (j + RMAX));
    else if (r == NREL - 1) cnt = max(0, j - RMAX + 1);
    else                    cnt = (j - v >= 0 && j - v < MN) ? 1 : 0;
    acc += (float)cnt * emb[(size_t)r * D3 + d];
  }
  psum[(size_t)j * D3 + d] = acc;
}

// ---------------------------------------------------------------------------
// rel-pos-enc closed form (elementwise)
// ---------------------------------------------------------------------------
__global__ __launch_bounds__(D3) void pe_kernel(
    const float* __restrict__ xm, const float* __restrict__ psum,
    const float* __restrict__ emb, const float* __restrict__ dww,
    const float* __restrict__ dwb, float* __restrict__ xpe) {
  const int bb_ = blockIdx.x / MN, j = blockIdx.x % MN;
  const int d = threadIdx.x;
  const size_t base = ((size_t)bb_ * MN + j) * D3 + d;
  float xc = xm[base];
  float fC = xc + emb[(size_t)RMAX * D3 + d];
  float fL = (j > 0)      ? xm[base - D3] + emb[(size_t)(RMAX - 1) * D3 + d] : 0.f;
  float fR = (j < MN - 1) ? xm[base + D3] + emb[(size_t)(RMAX + 1) * D3 + d] : 0.f;
  float dc = fL * dww[d * 3 + 0] + fC * dww[d * 3 + 1] + fR * dww[d * 3 + 2] + dwb[d];
  xpe[base] = xc + (psum[(size_t)j * D3 + d] - fC + dc) * (1.f / MN);
}

// ---------------------------------------------------------------------------
// MFMA flash attention (transposed-operand scheme).
// Grid = B*NH*(L/64); block = 4 waves, wave w owns 16 q-rows (q0 = qc*64+w*16).
// S^T tile = mfma(A=K[16key,32dk], B=Q^T[32dk,16q]): C col=lane&15=q,
// row=quad*4+reg=key -> softmax column ops are per-lane + shfl_xor(16,32).
// P^T goes through per-wave-private LDS (C-layout ushort4 writes; read back as
// contiguous B-frag rows). O^T = mfma(A=V^T[16dk,32key], B=P^T[32key,16q]).
// No __syncthreads anywhere; waves fully independent.
// ---------------------------------------------------------------------------
#define PROW 136  // P^T LDS row stride (ushorts): 272 B = 17*16 -> b128-aligned, 2-way-max banks
__global__ __launch_bounds__(256, 1) void attn_mfma_kernel(
    const ushort* __restrict__ Qb, const ushort* __restrict__ Kb,
    const ushort* __restrict__ Vt, float* __restrict__ Ao) {
  const int blk = blockIdx.x;
  const int qc = blk & 15;
  const int h  = (blk >> 4) & 7;
  const int b_ = blk >> 7;
  const int tid = threadIdx.x;
  const int wave = tid >> 6, lane = tid & 63;
  const int q15 = lane & 15, quad = lane >> 4;
  const int q0 = qc * 64 + wave * 16;

  __shared__ ushort Plds[4][16][PROW];
  ushort* prow = &Plds[wave][q15][0];

  // B-frag: B[k=dk][n=q], n=lane&15 -> Q row q0+q15, k=quad*8+j -> col offset
  const bf16x8 qfrag = ldbf8(Qb + ((size_t)(b_ * L + q0 + q15)) * DM + h * DK + quad * 8);

  f32x4 o0 = {0.f, 0.f, 0.f, 0.f}, o1 = {0.f, 0.f, 0.f, 0.f};
  float mrun = -1e30f, lsum = 0.f;
  const float scale = 0.17677669529663687f;  // 1/sqrt(32)

  const ushort* kbase = Kb + ((size_t)(b_ * MN) + q15) * DM + h * DK + quad * 8;
  const ushort* vbase = Vt + ((size_t)((b_ * NH + h) * DK) + q15) * MN;

  for (int c = 0; c < 4; ++c) {
    const int kb0 = c * 128;
    f32x4 s[8];
#pragma unroll
    for (int t = 0; t < 8; ++t) {
      bf16x8 af = ldbf8(kbase + (size_t)(kb0 + t * 16) * DM);  // A[m=key][k=dk]
      f32x4 z = {0.f, 0.f, 0.f, 0.f};
      s[t] = __builtin_amdgcn_mfma_f32_16x16x32_bf16(af, qfrag, z, 0, 0, 0);
    }
    float ml = -1e30f;
#pragma unroll
    for (int t = 0; t < 8; ++t)
#pragma unroll
      for (int r = 0; r < 4; ++r) { s[t][r] *= scale; ml = fmaxf(ml, s[t][r]); }
    ml = fmaxf(ml, __shfl_xor(ml, 16));
    ml = fmaxf(ml, __shfl_xor(ml, 32));
    float mnew = fmaxf(mrun, ml);
    float alpha = __expf(mrun - mnew);
    mrun = mnew;
    lsum *= alpha;
#pragma unroll
    for (int r = 0; r < 4; ++r) { o0[r] *= alpha; o1[r] *= alpha; }
#pragma unroll
    for (int t = 0; t < 8; ++t) {
      float p0 = __expf(s[t][0] - mrun), p1 = __expf(s[t][1] - mrun);
      float p2 = __expf(s[t][2] - mrun), p3 = __expf(s[t][3] - mrun);
      lsum += (p0 + p1) + (p2 + p3);
      ushort4 pk = make_ushort4(f2bf(p0), f2bf(p1), f2bf(p2), f2bf(p3));
      *(ushort4*)(prow + t * 16 + quad * 4) = pk;   // P^T[key=t*16+quad*4+r][q]
    }
    // same-wave LDS RAW: compiler inserts lgkmcnt wait
#pragma unroll
    for (int t2 = 0; t2 < 4; ++t2) {
      bf16x8 bfr = ldbf8(prow + t2 * 32 + quad * 8);                 // B[k=key][n=q]
      bf16x8 av0 = ldbf8(vbase + (size_t)(kb0 + t2 * 32 + quad * 8)); // A[m=dk 0-15][k=key]
      bf16x8 av1 = ldbf8(vbase + (size_t)16 * MN + (kb0 + t2 * 32 + quad * 8));
      o0 = __builtin_amdgcn_mfma_f32_16x16x32_bf16(av0, bfr, o0, 0, 0, 0);
      o1 = __builtin_amdgcn_mfma_f32_16x16x32_bf16(av1, bfr, o1, 0, 0, 0);
    }
  }
  lsum += __shfl_xor(lsum, 16);
  lsum += __shfl_xor(lsum, 32);
  float rinv = 1.f / lsum;
  // O^T C-layout: col=lane&15=q, row=quad*4+reg=dk_local (o1 -> +16)
  float* obase = Ao + ((size_t)(b_ * L + q0 + q15)) * DM + h * DK + quad * 4;
  *(float4*)(obase)      = make_float4(o0[0] * rinv, o0[1] * rinv, o0[2] * rinv, o0[3] * rinv);
  *(float4*)(obase + 16) = make_float4(o1[0] * rinv, o1[1] * rinv, o1[2] * rinv, o1[3] * rinv);
}

// ---------------------------------------------------------------------------
// Final: fc + Gamma-tile gating + residual + LayerNorm
// ---------------------------------------------------------------------------
template<int RPB>
__global__ __launch_bounds__(256) void final_kernel(
    const float* __restrict__ A, const float* __restrict__ fcw,
    const float* __restrict__ fcb, const float* __restrict__ G,
    const float* __restrict__ Xs, const float* __restrict__ lnw,
    const float* __restrict__ lnb, float* __restrict__ out) {
  const int row0 = blockIdx.x * RPB;
  const int d = threadIdx.x;
  __shared__ float xs[RPB][DM];
  float* xsf = &xs[0][0];
  for (int i = d * 4; i < RPB * DM; i += 256 * 4)
    *(float4*)(xsf + i) = *(const float4*)(A + (size_t)row0 * DM + i);
  __syncthreads();
  float acc[RPB];
  const float bv = fcb[d];
#pragma unroll
  for (int r = 0; r < RPB; ++r) acc[r] = bv;
  const float* w = fcw + (size_t)d * DM;
  for (int c = 0; c < DM; c += 4) {
    float4 w4 = *(const float4*)(w + c);
#pragma unroll
    for (int r = 0; r < RPB; ++r) {
      float4 x4 = *(const float4*)&xs[r][c];
      acc[r] += x4.x * w4.x + x4.y * w4.y + x4.z * w4.z + x4.w * w4.w;
    }
  }
  float v[RPB];
#pragma unroll
  for (int r = 0; r < RPB; ++r) {
    int row = row0 + r;
    int bb_ = row >> 10;
    int l   = row & 1023;
    float g = G[((size_t)bb_ * MN + (l & 511)) * DM + d];
    v[r] = Xs[(size_t)row * SD + d] + g * acc[r];
  }
  __shared__ float p1[RPB][4], p2[RPB][4];
#pragma unroll
  for (int r = 0; r < RPB; ++r) {
    float s1 = v[r], s2 = v[r] * v[r];
    for (int o = 32; o > 0; o >>= 1) {
      s1 += __shfl_down(s1, o);
      s2 += __shfl_down(s2, o);
    }
    if ((d & 63) == 0) { p1[r][d >> 6] = s1; p2[r][d >> 6] = s2; }
  }
  __syncthreads();
#pragma unroll
  for (int r = 0; r < RPB; ++r) {
    float t1 = p1[r][0] + p1[r][1] + p1[r][2] + p1[r][3];
    float t2 = p2[r][0] + p2[r][1] + p2[r][2] + p2[r][3];
    float mu = t1 * (1.f / DM);
    float var = t2 * (1.f / DM) - mu * mu;
    float rs = rsqrtf(var + 1e-5f);
    out[(size_t)(row0 + r) * DM + d] = (v[r] - mu) * rs * lnw[d] + lnb[d];
  }
}

// ---------------------------------------------------------------------------
extern "C" void kernel_launch(void* const* d_in, const int* in_sizes, int n_in,
                              void* d_out, int out_size, void* d_ws, size_t ws_size,
                              hipStream_t stream) {
  const float* x_spatial  = (const float*)d_in[0];
  const float* x_velocity = (const float*)d_in[1];
  const float* Wg   = (const float*)d_in[2];
  const float* w3   = (const float*)d_in[3];
  const float* b3   = (const float*)d_in[4];
  const float* w5   = (const float*)d_in[5];
  const float* b5   = (const float*)d_in[6];
  const float* w7   = (const float*)d_in[7];
  const float* b7   = (const float*)d_in[8];
  const float* remb = (const float*)d_in[9];
  const float* dww  = (const float*)d_in[10];
  const float* dwb  = (const float*)d_in[11];
  const float* Wq   = (const float*)d_in[12];
  const float* Wk   = (const float*)d_in[13];
  const float* Wv   = (const float*)d_in[14];
  const float* fcw  = (const float*)d_in[15];
  const float* fcb  = (const float*)d_in[16];
  const float* lnw  = (const float*)d_in[17];
  const float* lnb  = (const float*)d_in[18];
  float* out = (float*)d_out;

  // workspace layout (bytes, 256-aligned); total 109.45 MB (same as R2 footprint)
  char* w8 = (char*)d_ws;
  float*  Gamma = (float*)(w8);                     // 16,777,216
  float*  xm    = (float*)(w8 + 16777216);          // 12,582,912
  float*  psum  = (float*)(w8 + 29360128);          //    393,216
  float*  xpe   = (float*)(w8 + 29753344);          // 12,582,912
  ushort* Qb    = (ushort*)(w8 + 42336256);         // 16,777,216 (bf16)
  ushort* Kp    = (ushort*)(w8 + 59113472);         //  8,388,608 (bf16)
  ushort* Vt    = (ushort*)(w8 + 67502080);         //  8,388,608 (bf16, per-head [dk][s])
  float*  Ao    = (float*)(w8 + 75890688);          // 33,554,432

  rowgemm_kernel<VD, 8, 1, 0><<<B * MN / 8, 256, 0, stream>>>(x_velocity, Wg, Gamma);
  msconv_kernel<8><<<B * MN / 8, 192, 0, stream>>>(x_velocity, w3, b3, w5, b5, w7, b7, xm);
  possum_kernel<<<MN, D3, 0, stream>>>(remb, psum);
  pe_kernel<<<B * MN, D3, 0, stream>>>(xm, psum, remb, dww, dwb, xpe);
  rowgemm_kernel<SD, 8, 0, 1><<<B * L / 8, 256, 0, stream>>>(x_spatial, Wq, Qb);
  rowgemm_kernel<D3, 8, 0, 1><<<B * MN / 8, 256, 0, stream>>>(xpe, Wk, Kp);
  rowgemm_kernel<D3, 8, 0, 2><<<B * MN / 8, 256, 0, stream>>>(xpe, Wv, Vt);
  attn_mfma_kernel<<<B * NH * (L / 64), 256, 0, stream>>>(Qb, Kp, Vt, Ao);
  final_kernel<8><<<B * L / 8, 256, 0, stream>>>(Ao, fcw, fcb, Gamma,
                                                 x_spatial, lnw, lnb, out);
}

// Round 4
// 738.939 us; speedup vs baseline: 2.1601x; 1.1768x over previous
//
#include <hip/hip_runtime.h>

#define B   32
#define L   1024
#define MN  512
#define SD  256
#define VD  64
#define DM  256
#define D3  192
#define NH  8
#define DK  32
#define RMAX 30
#define NREL 61

typedef __attribute__((ext_vector_type(8))) __bf16 bf16x8;
typedef __attribute__((ext_vector_type(4))) float  f32x4;

static __device__ __forceinline__ ushort f2bf(float f) {
  unsigned u = __float_as_uint(f);
  unsigned r = (u + 0x7FFFu + ((u >> 16) & 1u)) >> 16;
  return (ushort)r;
}
static __device__ __forceinline__ bf16x8 ldbf8(const ushort* p) {
  return __builtin_bit_cast(bf16x8, *(const uint4*)p);
}

// ---------------------------------------------------------------------------
// Row-GEMM: Y[row, d] = act( sum_c X[row, c] * W[d, c] ), 256 out channels.
// OMODE: 0 = f32 [row][DM]; 1 = bf16 [row][DM]; 2 = bf16 V^T [b][h][dk][s]
// ACT: 0 = none, 1 = sigmoid
// ---------------------------------------------------------------------------
template<int CIN, int RPB, int ACT, int OMODE>
__global__ __launch_bounds__(256) void rowgemm_kernel(
    const float* __restrict__ X, const float* __restrict__ W, void* Yv) {
  const int row0 = blockIdx.x * RPB;
  const int d = threadIdx.x;
  __shared__ float xs[RPB][CIN];
  float* xsf = &xs[0][0];
  for (int i = d * 4; i < RPB * CIN; i += 256 * 4)
    *(float4*)(xsf + i) = *(const float4*)(X + (size_t)row0 * CIN + i);
  __syncthreads();
  float acc[RPB];
#pragma unroll
  for (int r = 0; r < RPB; ++r) acc[r] = 0.f;
  const float* w = W + (size_t)d * CIN;
  for (int c = 0; c < CIN; c += 4) {
    float4 w4 = *(const float4*)(w + c);
#pragma unroll
    for (int r = 0; r < RPB; ++r) {
      float4 x4 = *(const float4*)&xs[r][c];
      acc[r] += x4.x * w4.x + x4.y * w4.y + x4.z * w4.z + x4.w * w4.w;
    }
  }
#pragma unroll
  for (int r = 0; r < RPB; ++r) {
    float o = acc[r];
    if (ACT == 1) o = 1.f / (1.f + __expf(-o));
    int row = row0 + r;
    if (OMODE == 0) {
      ((float*)Yv)[(size_t)row * DM + d] = o;
    } else if (OMODE == 1) {
      ((ushort*)Yv)[(size_t)row * DM + d] = f2bf(o);
    } else {
      int b_ = row >> 9, s = row & 511;
      ((ushort*)Yv)[((size_t)((b_ * NH + (d >> 5)) * DK + (d & 31))) * MN + s] = f2bf(o);
    }
  }
}

// ---------------------------------------------------------------------------
// Multi-scale conv1d (K=3,5,7), 'same' padding, concat -> [.,.,192].
// R3 post-mortem: was latency-bound (VALUBusy 15%) on serial scalar weight
// loads. Now: channel loop chunked by 4, weights preloaded as K float4s into
// regs (deep MLP, 4x fewer loads), FMAs run against LDS-broadcast x.
// ---------------------------------------------------------------------------
template<int K, int KOFF, int RPB>
__device__ __forceinline__ void conv_scale(
    const float* __restrict__ wrow, float bias,
    const float (*xs)[VD], float* __restrict__ acc) {
#pragma unroll
  for (int r = 0; r < RPB; ++r) acc[r] = bias;
#pragma unroll 2
  for (int i0 = 0; i0 < VD; i0 += 4) {
    float4 wf[K];
#pragma unroll
    for (int j = 0; j < K; ++j) wf[j] = *(const float4*)(wrow + i0 * K + j * 4);
    const float* wv = (const float*)wf;
#pragma unroll
    for (int i = 0; i < 4; ++i)
#pragma unroll
      for (int k = 0; k < K; ++k) {
        float w1 = wv[i * K + k];
#pragma unroll
        for (int r = 0; r < RPB; ++r)
          acc[r] += xs[r + k + KOFF][i0 + i] * w1;
      }
  }
}

template<int RPB>
__global__ __launch_bounds__(192) void msconv_kernel(
    const float* __restrict__ xv,
    const float* __restrict__ w3, const float* __restrict__ b3,
    const float* __restrict__ w5, const float* __restrict__ b5,
    const float* __restrict__ w7, const float* __restrict__ b7,
    float* __restrict__ xm) {
  const int bb_ = blockIdx.x / (MN / RPB);
  const int s0  = (blockIdx.x % (MN / RPB)) * RPB;
  const int t = threadIdx.x;
  __shared__ float xs[RPB + 6][VD];
  for (int i = t; i < (RPB + 6) * VD; i += 192) {
    int r = i / VD, c = i % VD;
    int ss = s0 + r - 3;
    xs[r][c] = (ss >= 0 && ss < MN) ? xv[((size_t)bb_ * MN + ss) * VD + c] : 0.f;
  }
  __syncthreads();
  const int scale = t / VD, o = t % VD;
  float acc[RPB];
  if (scale == 0)
    conv_scale<3, 2, RPB>(w3 + (size_t)o * VD * 3, b3[o], xs, acc);
  else if (scale == 1)
    conv_scale<5, 1, RPB>(w5 + (size_t)o * VD * 5, b5[o], xs, acc);
  else
    conv_scale<7, 0, RPB>(w7 + (size_t)o * VD * 7, b7[o], xs, acc);
#pragma unroll
  for (int r = 0; r < RPB; ++r)
    xm[((size_t)bb_ * MN + s0 + r) * D3 + scale * VD + o] = acc[r];
}

// ---------------------------------------------------------------------------
// pos_sum[j, d] = sum_i emb[clip(j-i, -R, R) + R, d]
// ---------------------------------------------------------------------------
__global__ __launch_bounds__(D3) void possum_kernel(
    const float* __restrict__ emb, float* __restrict__ psum) {
  const int j = blockIdx.x, d = threadIdx.x;
  float acc = 0.f;
  for (int r = 0; r < NREL; ++r) {
    int v = r - RMAX;
    int cnt;
    if (r == 0)             cnt = max(0, MN - (j + RMAX));
    else if (r == NREL - 1) cnt = max(0, j - RMAX + 1);
    else                    cnt = (j - v >= 0 && j - v < MN) ? 1 : 0;
    acc += (float)cnt * emb[(size_t)r * D3 + d];
  }
  psum[(size_t)j * D3 + d] = acc;
}

// ---------------------------------------------------------------------------
// rel-pos-enc closed form (elementwise)
// ---------------------------------------------------------------------------
__global__ __launch_bounds__(D3) void pe_kernel(
    const float* __restrict__ xm, const float* __restrict__ psum,
    const float* __restrict__ emb, const float* __restrict__ dww,
    const float* __restrict__ dwb, float* __restrict__ xpe) {
  const int bb_ = blockIdx.x / MN, j = blockIdx.x % MN;
  const int d = threadIdx.x;
  const size_t base = ((size_t)bb_ * MN + j) * D3 + d;
  float xc = xm[base];
  float fC = xc + emb[(size_t)RMAX * D3 + d];
  float fL = (j > 0)      ? xm[base - D3] + emb[(size_t)(RMAX - 1) * D3 + d] : 0.f;
  float fR = (j < MN - 1) ? xm[base + D3] + emb[(size_t)(RMAX + 1) * D3 + d] : 0.f;
  float dc = fL * dww[d * 3 + 0] + fC * dww[d * 3 + 1] + fR * dww[d * 3 + 2] + dwb[d];
  xpe[base] = xc + (psum[(size_t)j * D3 + d] - fC + dc) * (1.f / MN);
}

// ---------------------------------------------------------------------------
// MFMA flash attention (transposed-operand scheme). See R2 notes.
// ---------------------------------------------------------------------------
#define PROW 136
__global__ __launch_bounds__(256, 1) void attn_mfma_kernel(
    const ushort* __restrict__ Qb, const ushort* __restrict__ Kb,
    const ushort* __restrict__ Vt, float* __restrict__ Ao) {
  const int blk = blockIdx.x;
  const int qc = blk & 15;
  const int h  = (blk >> 4) & 7;
  const int b_ = blk >> 7;
  const int tid = threadIdx.x;
  const int wave = tid >> 6, lane = tid & 63;
  const int q15 = lane & 15, quad = lane >> 4;
  const int q0 = qc * 64 + wave * 16;

  __shared__ ushort Plds[4][16][PROW];
  ushort* prow = &Plds[wave][q15][0];

  const bf16x8 qfrag = ldbf8(Qb + ((size_t)(b_ * L + q0 + q15)) * DM + h * DK + quad * 8);

  f32x4 o0 = {0.f, 0.f, 0.f, 0.f}, o1 = {0.f, 0.f, 0.f, 0.f};
  float mrun = -1e30f, lsum = 0.f;
  const float scale = 0.17677669529663687f;  // 1/sqrt(32)

  const ushort* kbase = Kb + ((size_t)(b_ * MN) + q15) * DM + h * DK + quad * 8;
  const ushort* vbase = Vt + ((size_t)((b_ * NH + h) * DK) + q15) * MN;

  for (int c = 0; c < 4; ++c) {
    const int kb0 = c * 128;
    f32x4 s[8];
#pragma unroll
    for (int t = 0; t < 8; ++t) {
      bf16x8 af = ldbf8(kbase + (size_t)(kb0 + t * 16) * DM);
      f32x4 z = {0.f, 0.f, 0.f, 0.f};
      s[t] = __builtin_amdgcn_mfma_f32_16x16x32_bf16(af, qfrag, z, 0, 0, 0);
    }
    float ml = -1e30f;
#pragma unroll
    for (int t = 0; t < 8; ++t)
#pragma unroll
      for (int r = 0; r < 4; ++r) { s[t][r] *= scale; ml = fmaxf(ml, s[t][r]); }
    ml = fmaxf(ml, __shfl_xor(ml, 16));
    ml = fmaxf(ml, __shfl_xor(ml, 32));
    float mnew = fmaxf(mrun, ml);
    float alpha = __expf(mrun - mnew);
    mrun = mnew;
    lsum *= alpha;
#pragma unroll
    for (int r = 0; r < 4; ++r) { o0[r] *= alpha; o1[r] *= alpha; }
#pragma unroll
    for (int t = 0; t < 8; ++t) {
      float p0 = __expf(s[t][0] - mrun), p1 = __expf(s[t][1] - mrun);
      float p2 = __expf(s[t][2] - mrun), p3 = __expf(s[t][3] - mrun);
      lsum += (p0 + p1) + (p2 + p3);
      ushort4 pk = make_ushort4(f2bf(p0), f2bf(p1), f2bf(p2), f2bf(p3));
      *(ushort4*)(prow + t * 16 + quad * 4) = pk;
    }
#pragma unroll
    for (int t2 = 0; t2 < 4; ++t2) {
      bf16x8 bfr = ldbf8(prow + t2 * 32 + quad * 8);
      bf16x8 av0 = ldbf8(vbase + (size_t)(kb0 + t2 * 32 + quad * 8));
      bf16x8 av1 = ldbf8(vbase + (size_t)16 * MN + (kb0 + t2 * 32 + quad * 8));
      o0 = __builtin_amdgcn_mfma_f32_16x16x32_bf16(av0, bfr, o0, 0, 0, 0);
      o1 = __builtin_amdgcn_mfma_f32_16x16x32_bf16(av1, bfr, o1, 0, 0, 0);
    }
  }
  lsum += __shfl_xor(lsum, 16);
  lsum += __shfl_xor(lsum, 32);
  float rinv = 1.f / lsum;
  float* obase = Ao + ((size_t)(b_ * L + q0 + q15)) * DM + h * DK + quad * 4;
  *(float4*)(obase)      = make_float4(o0[0] * rinv, o0[1] * rinv, o0[2] * rinv, o0[3] * rinv);
  *(float4*)(obase + 16) = make_float4(o1[0] * rinv, o1[1] * rinv, o1[2] * rinv, o1[3] * rinv);
}

// ---------------------------------------------------------------------------
// Final: fc + Gamma-tile gating + residual + LayerNorm
// ---------------------------------------------------------------------------
template<int RPB>
__global__ __launch_bounds__(256) void final_kernel(
    const float* __restrict__ A, const float* __restrict__ fcw,
    const float* __restrict__ fcb, const float* __restrict__ G,
    const float* __restrict__ Xs, const float* __restrict__ lnw,
    const float* __restrict__ lnb, float* __restrict__ out) {
  const int row0 = blockIdx.x * RPB;
  const int d = threadIdx.x;
  __shared__ float xs[RPB][DM];
  float* xsf = &xs[0][0];
  for (int i = d * 4; i < RPB * DM; i += 256 * 4)
    *(float4*)(xsf + i) = *(const float4*)(A + (size_t)row0 * DM + i);
  __syncthreads();
  float acc[RPB];
  const float bv = fcb[d];
#pragma unroll
  for (int r = 0; r < RPB; ++r) acc[r] = bv;
  const float* w = fcw + (size_t)d * DM;
  for (int c = 0; c < DM; c += 4) {
    float4 w4 = *(const float4*)(w + c);
#pragma unroll
    for (int r = 0; r < RPB; ++r) {
      float4 x4 = *(const float4*)&xs[r][c];
      acc[r] += x4.x * w4.x + x4.y * w4.y + x4.z * w4.z + x4.w * w4.w;
    }
  }
  float v[RPB];
#pragma unroll
  for (int r = 0; r < RPB; ++r) {
    int row = row0 + r;
    int bb_ = row >> 10;
    int l   = row & 1023;
    float g = G[((size_t)bb_ * MN + (l & 511)) * DM + d];
    v[r] = Xs[(size_t)row * SD + d] + g * acc[r];
  }
  __shared__ float p1[RPB][4], p2[RPB][4];
#pragma unroll
  for (int r = 0; r < RPB; ++r) {
    float s1 = v[r], s2 = v[r] * v[r];
    for (int o = 32; o > 0; o >>= 1) {
      s1 += __shfl_down(s1, o);
      s2 += __shfl_down(s2, o);
    }
    if ((d & 63) == 0) { p1[r][d >> 6] = s1; p2[r][d >> 6] = s2; }
  }
  __syncthreads();
#pragma unroll
  for (int r = 0; r < RPB; ++r) {
    float t1 = p1[r][0] + p1[r][1] + p1[r][2] + p1[r][3];
    float t2 = p2[r][0] + p2[r][1] + p2[r][2] + p2[r][3];
    float mu = t1 * (1.f / DM);
    float var = t2 * (1.f / DM) - mu * mu;
    float rs = rsqrtf(var + 1e-5f);
    out[(size_t)(row0 + r) * DM + d] = (v[r] - mu) * rs * lnw[d] + lnb[d];
  }
}

// ---------------------------------------------------------------------------
extern "C" void kernel_launch(void* const* d_in, const int* in_sizes, int n_in,
                              void* d_out, int out_size, void* d_ws, size_t ws_size,
                              hipStream_t stream) {
  const float* x_spatial  = (const float*)d_in[0];
  const float* x_velocity = (const float*)d_in[1];
  const float* Wg   = (const float*)d_in[2];
  const float* w3   = (const float*)d_in[3];
  const float* b3   = (const float*)d_in[4];
  const float* w5   = (const float*)d_in[5];
  const float* b5   = (const float*)d_in[6];
  const float* w7   = (const float*)d_in[7];
  const float* b7   = (const float*)d_in[8];
  const float* remb = (const float*)d_in[9];
  const float* dww  = (const float*)d_in[10];
  const float* dwb  = (const float*)d_in[11];
  const float* Wq   = (const float*)d_in[12];
  const float* Wk   = (const float*)d_in[13];
  const float* Wv   = (const float*)d_in[14];
  const float* fcw  = (const float*)d_in[15];
  const float* fcb  = (const float*)d_in[16];
  const float* lnw  = (const float*)d_in[17];
  const float* lnb  = (const float*)d_in[18];
  float* out = (float*)d_out;

  char* w8 = (char*)d_ws;
  float*  Gamma = (float*)(w8);                     // 16,777,216
  float*  xm    = (float*)(w8 + 16777216);          // 12,582,912
  float*  psum  = (float*)(w8 + 29360128);          //    393,216
  float*  xpe   = (float*)(w8 + 29753344);          // 12,582,912
  ushort* Qb    = (ushort*)(w8 + 42336256);         // 16,777,216 (bf16)
  ushort* Kp    = (ushort*)(w8 + 59113472);         //  8,388,608 (bf16)
  ushort* Vt    = (ushort*)(w8 + 67502080);         //  8,388,608 (bf16, per-head [dk][s])
  float*  Ao    = (float*)(w8 + 75890688);          // 33,554,432

  rowgemm_kernel<VD, 8, 1, 0><<<B * MN / 8, 256, 0, stream>>>(x_velocity, Wg, Gamma);
  msconv_kernel<8><<<B * MN / 8, 192, 0, stream>>>(x_velocity, w3, b3, w5, b5, w7, b7, xm);
  possum_kernel<<<MN, D3, 0, stream>>>(remb, psum);
  pe_kernel<<<B * MN, D3, 0, stream>>>(xm, psum, remb, dww, dwb, xpe);
  rowgemm_kernel<SD, 8, 0, 1><<<B * L / 8, 256, 0, stream>>>(x_spatial, Wq, Qb);
  rowgemm_kernel<D3, 8, 0, 1><<<B * MN / 8, 256, 0, stream>>>(xpe, Wk, Kp);
  rowgemm_kernel<D3, 8, 0, 2><<<B * MN / 8, 256, 0, stream>>>(xpe, Wv, Vt);
  attn_mfma_kernel<<<B * NH * (L / 64), 256, 0, stream>>>(Qb, Kp, Vt, Ao);
  final_kernel<8><<<B * L / 8, 256, 0, stream>>>(Ao, fcw, fcb, Gamma,
                                                 x_spatial, lnw, lnb, out);
}

// Round 5
// 639.901 us; speedup vs baseline: 2.4945x; 1.1548x over previous
//
#include <hip/hip_runtime.h>

#define B   32
#define L   1024
#define MN  512
#define SD  256
#define VD  64
#define DM  256
#define D3  192
#define NH  8
#define DK  32
#define RMAX 30
#define NREL 61

typedef __attribute__((ext_vector_type(8))) __bf16 bf16x8;
typedef __attribute__((ext_vector_type(4))) float  f32x4;

static __device__ __forceinline__ ushort f2bf(float f) {
  unsigned u = __float_as_uint(f);
  unsigned r = (u + 0x7FFFu + ((u >> 16) & 1u)) >> 16;
  return (ushort)r;
}
static __device__ __forceinline__ bf16x8 ldbf8(const ushort* p) {
  return __builtin_bit_cast(bf16x8, *(const uint4*)p);
}

// ---------------------------------------------------------------------------
// Row-GEMM: Y[row, d] = act( sum_c X[row, c] * W[d, c] ), 256 out channels.
// OMODE: 0 = f32 [row][DM]; 1 = bf16 [row][DM]; 2 = bf16 V^T [b][h][dk][s]
// ---------------------------------------------------------------------------
template<int CIN, int RPB, int ACT, int OMODE>
__global__ __launch_bounds__(256) void rowgemm_kernel(
    const float* __restrict__ X, const float* __restrict__ W, void* Yv) {
  const int row0 = blockIdx.x * RPB;
  const int d = threadIdx.x;
  __shared__ float xs[RPB][CIN];
  float* xsf = &xs[0][0];
  for (int i = d * 4; i < RPB * CIN; i += 256 * 4)
    *(float4*)(xsf + i) = *(const float4*)(X + (size_t)row0 * CIN + i);
  __syncthreads();
  float acc[RPB];
#pragma unroll
  for (int r = 0; r < RPB; ++r) acc[r] = 0.f;
  const float* w = W + (size_t)d * CIN;
  for (int c = 0; c < CIN; c += 4) {
    float4 w4 = *(const float4*)(w + c);
#pragma unroll
    for (int r = 0; r < RPB; ++r) {
      float4 x4 = *(const float4*)&xs[r][c];
      acc[r] += x4.x * w4.x + x4.y * w4.y + x4.z * w4.z + x4.w * w4.w;
    }
  }
#pragma unroll
  for (int r = 0; r < RPB; ++r) {
    float o = acc[r];
    if (ACT == 1) o = 1.f / (1.f + __expf(-o));
    int row = row0 + r;
    if (OMODE == 0) {
      ((float*)Yv)[(size_t)row * DM + d] = o;
    } else if (OMODE == 1) {
      ((ushort*)Yv)[(size_t)row * DM + d] = f2bf(o);
    } else {
      int b_ = row >> 9, s = row & 511;
      ((ushort*)Yv)[((size_t)((b_ * NH + (d >> 5)) * DK + (d & 31))) * MN + s] = f2bf(o);
    }
  }
}

// ---------------------------------------------------------------------------
// f32 -> bf16 bulk convert (for fc weight)
// ---------------------------------------------------------------------------
__global__ __launch_bounds__(256) void tobf_kernel(
    const float* __restrict__ src, ushort* __restrict__ dst) {
  int i = (blockIdx.x * 256 + threadIdx.x) * 4;
  float4 v = *(const float4*)(src + i);
  *(ushort4*)(dst + i) = make_ushort4(f2bf(v.x), f2bf(v.y), f2bf(v.z), f2bf(v.w));
}

// ---------------------------------------------------------------------------
// Multi-scale conv1d (K=3,5,7) — R4 reg-preloaded weights version.
// ---------------------------------------------------------------------------
template<int K, int KOFF, int RPB>
__device__ __forceinline__ void conv_scale(
    const float* __restrict__ wrow, float bias,
    const float (*xs)[VD], float* __restrict__ acc) {
#pragma unroll
  for (int r = 0; r < RPB; ++r) acc[r] = bias;
#pragma unroll 2
  for (int i0 = 0; i0 < VD; i0 += 4) {
    float4 wf[K];
#pragma unroll
    for (int j = 0; j < K; ++j) wf[j] = *(const float4*)(wrow + i0 * K + j * 4);
    const float* wv = (const float*)wf;
#pragma unroll
    for (int i = 0; i < 4; ++i)
#pragma unroll
      for (int k = 0; k < K; ++k) {
        float w1 = wv[i * K + k];
#pragma unroll
        for (int r = 0; r < RPB; ++r)
          acc[r] += xs[r + k + KOFF][i0 + i] * w1;
      }
  }
}

template<int RPB>
__global__ __launch_bounds__(192) void msconv_kernel(
    const float* __restrict__ xv,
    const float* __restrict__ w3, const float* __restrict__ b3,
    const float* __restrict__ w5, const float* __restrict__ b5,
    const float* __restrict__ w7, const float* __restrict__ b7,
    float* __restrict__ xm) {
  const int bb_ = blockIdx.x / (MN / RPB);
  const int s0  = (blockIdx.x % (MN / RPB)) * RPB;
  const int t = threadIdx.x;
  __shared__ float xs[RPB + 6][VD];
  for (int i = t; i < (RPB + 6) * VD; i += 192) {
    int r = i / VD, c = i % VD;
    int ss = s0 + r - 3;
    xs[r][c] = (ss >= 0 && ss < MN) ? xv[((size_t)bb_ * MN + ss) * VD + c] : 0.f;
  }
  __syncthreads();
  const int scale = t / VD, o = t % VD;
  float acc[RPB];
  if (scale == 0)
    conv_scale<3, 2, RPB>(w3 + (size_t)o * VD * 3, b3[o], xs, acc);
  else if (scale == 1)
    conv_scale<5, 1, RPB>(w5 + (size_t)o * VD * 5, b5[o], xs, acc);
  else
    conv_scale<7, 0, RPB>(w7 + (size_t)o * VD * 7, b7[o], xs, acc);
#pragma unroll
  for (int r = 0; r < RPB; ++r)
    xm[((size_t)bb_ * MN + s0 + r) * D3 + scale * VD + o] = acc[r];
}

// ---------------------------------------------------------------------------
// pos_sum[j, d] = sum_i emb[clip(j-i, -R, R) + R, d]
// ---------------------------------------------------------------------------
__global__ __launch_bounds__(D3) void possum_kernel(
    const float* __restrict__ emb, float* __restrict__ psum) {
  const int j = blockIdx.x, d = threadIdx.x;
  float acc = 0.f;
  for (int r = 0; r < NREL; ++r) {
    int v = r - RMAX;
    int cnt;
    if (r == 0)             cnt = max(0, MN - (j + RMAX));
    else if (r == NREL - 1) cnt = max(0, j - RMAX + 1);
    else                    cnt = (j - v >= 0 && j - v < MN) ? 1 : 0;
    acc += (float)cnt * emb[(size_t)r * D3 + d];
  }
  psum[(size_t)j * D3 + d] = acc;
}

// ---------------------------------------------------------------------------
// rel-pos-enc closed form (elementwise)
// ---------------------------------------------------------------------------
__global__ __launch_bounds__(D3) void pe_kernel(
    const float* __restrict__ xm, const float* __restrict__ psum,
    const float* __restrict__ emb, const float* __restrict__ dww,
    const float* __restrict__ dwb, float* __restrict__ xpe) {
  const int bb_ = blockIdx.x / MN, j = blockIdx.x % MN;
  const int d = threadIdx.x;
  const size_t base = ((size_t)bb_ * MN + j) * D3 + d;
  float xc = xm[base];
  float fC = xc + emb[(size_t)RMAX * D3 + d];
  float fL = (j > 0)      ? xm[base - D3] + emb[(size_t)(RMAX - 1) * D3 + d] : 0.f;
  float fR = (j < MN - 1) ? xm[base + D3] + emb[(size_t)(RMAX + 1) * D3 + d] : 0.f;
  float dc = fL * dww[d * 3 + 0] + fC * dww[d * 3 + 1] + fR * dww[d * 3 + 2] + dwb[d];
  xpe[base] = xc + (psum[(size_t)j * D3 + d] - fC + dc) * (1.f / MN);
}

// ---------------------------------------------------------------------------
// MFMA flash attention (transposed-operand scheme, R2/R3). Output now bf16.
// ---------------------------------------------------------------------------
#define PROW 136
__global__ __launch_bounds__(256, 1) void attn_mfma_kernel(
    const ushort* __restrict__ Qb, const ushort* __restrict__ Kb,
    const ushort* __restrict__ Vt, ushort* __restrict__ Ao) {
  const int blk = blockIdx.x;
  const int qc = blk & 15;
  const int h  = (blk >> 4) & 7;
  const int b_ = blk >> 7;
  const int tid = threadIdx.x;
  const int wave = tid >> 6, lane = tid & 63;
  const int q15 = lane & 15, quad = lane >> 4;
  const int q0 = qc * 64 + wave * 16;

  __shared__ ushort Plds[4][16][PROW];
  ushort* prow = &Plds[wave][q15][0];

  const bf16x8 qfrag = ldbf8(Qb + ((size_t)(b_ * L + q0 + q15)) * DM + h * DK + quad * 8);

  f32x4 o0 = {0.f, 0.f, 0.f, 0.f}, o1 = {0.f, 0.f, 0.f, 0.f};
  float mrun = -1e30f, lsum = 0.f;
  const float scale = 0.17677669529663687f;  // 1/sqrt(32)

  const ushort* kbase = Kb + ((size_t)(b_ * MN) + q15) * DM + h * DK + quad * 8;
  const ushort* vbase = Vt + ((size_t)((b_ * NH + h) * DK) + q15) * MN;

  for (int c = 0; c < 4; ++c) {
    const int kb0 = c * 128;
    f32x4 s[8];
#pragma unroll
    for (int t = 0; t < 8; ++t) {
      bf16x8 af = ldbf8(kbase + (size_t)(kb0 + t * 16) * DM);
      f32x4 z = {0.f, 0.f, 0.f, 0.f};
      s[t] = __builtin_amdgcn_mfma_f32_16x16x32_bf16(af, qfrag, z, 0, 0, 0);
    }
    float ml = -1e30f;
#pragma unroll
    for (int t = 0; t < 8; ++t)
#pragma unroll
      for (int r = 0; r < 4; ++r) { s[t][r] *= scale; ml = fmaxf(ml, s[t][r]); }
    ml = fmaxf(ml, __shfl_xor(ml, 16));
    ml = fmaxf(ml, __shfl_xor(ml, 32));
    float mnew = fmaxf(mrun, ml);
    float alpha = __expf(mrun - mnew);
    mrun = mnew;
    lsum *= alpha;
#pragma unroll
    for (int r = 0; r < 4; ++r) { o0[r] *= alpha; o1[r] *= alpha; }
#pragma unroll
    for (int t = 0; t < 8; ++t) {
      float p0 = __expf(s[t][0] - mrun), p1 = __expf(s[t][1] - mrun);
      float p2 = __expf(s[t][2] - mrun), p3 = __expf(s[t][3] - mrun);
      lsum += (p0 + p1) + (p2 + p3);
      ushort4 pk = make_ushort4(f2bf(p0), f2bf(p1), f2bf(p2), f2bf(p3));
      *(ushort4*)(prow + t * 16 + quad * 4) = pk;
    }
#pragma unroll
    for (int t2 = 0; t2 < 4; ++t2) {
      bf16x8 bfr = ldbf8(prow + t2 * 32 + quad * 8);
      bf16x8 av0 = ldbf8(vbase + (size_t)(kb0 + t2 * 32 + quad * 8));
      bf16x8 av1 = ldbf8(vbase + (size_t)16 * MN + (kb0 + t2 * 32 + quad * 8));
      o0 = __builtin_amdgcn_mfma_f32_16x16x32_bf16(av0, bfr, o0, 0, 0, 0);
      o1 = __builtin_amdgcn_mfma_f32_16x16x32_bf16(av1, bfr, o1, 0, 0, 0);
    }
  }
  lsum += __shfl_xor(lsum, 16);
  lsum += __shfl_xor(lsum, 32);
  float rinv = 1.f / lsum;
  ushort* obase = Ao + ((size_t)(b_ * L + q0 + q15)) * DM + h * DK + quad * 4;
  *(ushort4*)(obase)      = make_ushort4(f2bf(o0[0] * rinv), f2bf(o0[1] * rinv),
                                         f2bf(o0[2] * rinv), f2bf(o0[3] * rinv));
  *(ushort4*)(obase + 16) = make_ushort4(f2bf(o1[0] * rinv), f2bf(o1[1] * rinv),
                                         f2bf(o1[2] * rinv), f2bf(o1[3] * rinv));
}

// ---------------------------------------------------------------------------
// Final via MFMA: fc (bf16 MFMA) + Gamma gating + residual + LayerNorm.
// R4 post-mortem: VALU version was LDS-issue-bound (512 ds_read_b128/thread,
// ~12cyc each = the whole 181 us). One wave = 16 rows; 16 col-tiles x 8
// k-steps of 16x16x32 MFMA; epilogue in C-layout registers, LN reduction =
// 4x shfl_xor over the 16-lane col group. Grid 512 = 2 blocks/CU.
// ---------------------------------------------------------------------------
__global__ __launch_bounds__(256, 2) void final_mfma_kernel(
    const ushort* __restrict__ Ao, const ushort* __restrict__ fcwb,
    const float* __restrict__ fcb, const float* __restrict__ G,
    const float* __restrict__ Xs, const float* __restrict__ lnw,
    const float* __restrict__ lnb, float* __restrict__ out) {
  const int tid = threadIdx.x;
  const int wave = tid >> 6, lane = tid & 63;
  const int q15 = lane & 15, quad = lane >> 4;
  const int row0 = blockIdx.x * 64 + wave * 16;

  f32x4 acc[16];
#pragma unroll
  for (int t = 0; t < 16; ++t) acc[t] = (f32x4){0.f, 0.f, 0.f, 0.f};

  const ushort* abase = Ao + (size_t)(row0 + q15) * DM + quad * 8;
  const ushort* bbase = fcwb + (size_t)q15 * DM + quad * 8;
#pragma unroll 2
  for (int ks = 0; ks < 8; ++ks) {
    bf16x8 af = ldbf8(abase + ks * 32);
#pragma unroll
    for (int t = 0; t < 16; ++t) {
      bf16x8 bf = ldbf8(bbase + (size_t)t * 16 * DM + ks * 32);
      acc[t] = __builtin_amdgcn_mfma_f32_16x16x32_bf16(af, bf, acc[t], 0, 0, 0);
    }
  }

  // epilogue: C[m=quad*4+reg][n=t*16+q15]
#pragma unroll
  for (int reg = 0; reg < 4; ++reg) {
    const int grow = row0 + quad * 4 + reg;
    const int b_ = grow >> 10;
    const int gl = (grow & 1023) & 511;
    const float* gbase = G + ((size_t)b_ * MN + gl) * DM + q15;
    const float* xbase = Xs + (size_t)grow * SD + q15;
    float vv[16];
    float s1 = 0.f, s2 = 0.f;
#pragma unroll
    for (int t = 0; t < 16; ++t) {
      int col = t * 16 + q15;
      float fcv = acc[t][reg] + fcb[col];
      float v = xbase[t * 16] + gbase[t * 16] * fcv;
      vv[t] = v; s1 += v; s2 += v * v;
    }
    s1 += __shfl_xor(s1, 1); s2 += __shfl_xor(s2, 1);
    s1 += __shfl_xor(s1, 2); s2 += __shfl_xor(s2, 2);
    s1 += __shfl_xor(s1, 4); s2 += __shfl_xor(s2, 4);
    s1 += __shfl_xor(s1, 8); s2 += __shfl_xor(s2, 8);
    float mu = s1 * (1.f / DM);
    float var = s2 * (1.f / DM) - mu * mu;
    float rs = rsqrtf(var + 1e-5f);
    float* obase = out + (size_t)grow * DM + q15;
#pragma unroll
    for (int t = 0; t < 16; ++t) {
      int col = t * 16 + q15;
      obase[t * 16] = (vv[t] - mu) * rs * lnw[col] + lnb[col];
    }
  }
}

// ---------------------------------------------------------------------------
extern "C" void kernel_launch(void* const* d_in, const int* in_sizes, int n_in,
                              void* d_out, int out_size, void* d_ws, size_t ws_size,
                              hipStream_t stream) {
  const float* x_spatial  = (const float*)d_in[0];
  const float* x_velocity = (const float*)d_in[1];
  const float* Wg   = (const float*)d_in[2];
  const float* w3   = (const float*)d_in[3];
  const float* b3   = (const float*)d_in[4];
  const float* w5   = (const float*)d_in[5];
  const float* b5   = (const float*)d_in[6];
  const float* w7   = (const float*)d_in[7];
  const float* b7   = (const float*)d_in[8];
  const float* remb = (const float*)d_in[9];
  const float* dww  = (const float*)d_in[10];
  const float* dwb  = (const float*)d_in[11];
  const float* Wq   = (const float*)d_in[12];
  const float* Wk   = (const float*)d_in[13];
  const float* Wv   = (const float*)d_in[14];
  const float* fcw  = (const float*)d_in[15];
  const float* fcb  = (const float*)d_in[16];
  const float* lnw  = (const float*)d_in[17];
  const float* lnb  = (const float*)d_in[18];
  float* out = (float*)d_out;

  char* w8 = (char*)d_ws;
  float*  Gamma = (float*)(w8);                     // 16,777,216
  float*  xm    = (float*)(w8 + 16777216);          // 12,582,912
  float*  psum  = (float*)(w8 + 29360128);          //    393,216
  float*  xpe   = (float*)(w8 + 29753344);          // 12,582,912
  ushort* Qb    = (ushort*)(w8 + 42336256);         // 16,777,216 (bf16)
  ushort* Kp    = (ushort*)(w8 + 59113472);         //  8,388,608 (bf16)
  ushort* Vt    = (ushort*)(w8 + 67502080);         //  8,388,608 (bf16, per-head [dk][s])
  ushort* Ao    = (ushort*)(w8 + 75890688);         // 16,777,216 (bf16)
  ushort* fcwb  = (ushort*)(w8 + 92667904);         //    131,072 (bf16)

  rowgemm_kernel<VD, 8, 1, 0><<<B * MN / 8, 256, 0, stream>>>(x_velocity, Wg, Gamma);
  msconv_kernel<8><<<B * MN / 8, 192, 0, stream>>>(x_velocity, w3, b3, w5, b5, w7, b7, xm);
  possum_kernel<<<MN, D3, 0, stream>>>(remb, psum);
  pe_kernel<<<B * MN, D3, 0, stream>>>(xm, psum, remb, dww, dwb, xpe);
  rowgemm_kernel<SD, 8, 0, 1><<<B * L / 8, 256, 0, stream>>>(x_spatial, Wq, Qb);
  rowgemm_kernel<D3, 8, 0, 1><<<B * MN / 8, 256, 0, stream>>>(xpe, Wk, Kp);
  rowgemm_kernel<D3, 8, 0, 2><<<B * MN / 8, 256, 0, stream>>>(xpe, Wv, Vt);
  tobf_kernel<<<DM * DM / 1024, 256, 0, stream>>>(fcw, fcwb);
  attn_mfma_kernel<<<B * NH * (L / 64), 256, 0, stream>>>(Qb, Kp, Vt, Ao);
  final_mfma_kernel<<<B * L / 64, 256, 0, stream>>>(Ao, fcwb, fcb, Gamma,
                                                    x_spatial, lnw, lnb, out);
}

// Round 6
// 487.797 us; speedup vs baseline: 3.2723x; 1.3118x over previous
//
#include <hip/hip_runtime.h>

#define B   32
#define L   1024
#define MN  512
#define SD  256
#define VD  64
#define DM  256
#define D3  192
#define NH  8
#define DK  32
#define RMAX 30
#define NREL 61

typedef __attribute__((ext_vector_type(8))) __bf16 bf16x8;
typedef __attribute__((ext_vector_type(4))) float  f32x4;

static __device__ __forceinline__ ushort f2bf(float f) {
  unsigned u = __float_as_uint(f);
  unsigned r = (u + 0x7FFFu + ((u >> 16) & 1u)) >> 16;
  return (ushort)r;
}
static __device__ __forceinline__ bf16x8 ldbf8(const ushort* p) {
  return __builtin_bit_cast(bf16x8, *(const uint4*)p);
}

// ---------------------------------------------------------------------------
// f32 -> bf16 bulk convert. size must be multiple of 1024.
// ---------------------------------------------------------------------------
__global__ __launch_bounds__(256) void tobf_kernel(
    const float* __restrict__ src, ushort* __restrict__ dst) {
  int i = (blockIdx.x * 256 + threadIdx.x) * 4;
  float4 v = *(const float4*)(src + i);
  *(ushort4*)(dst + i) = make_ushort4(f2bf(v.x), f2bf(v.y), f2bf(v.z), f2bf(v.w));
}

// ---------------------------------------------------------------------------
// MFMA projection: Y[row, col] = act( sum_c Xb[row,c] * Wb[col,c] ), 256 cols.
// R5 post-mortem: VALU rowgemm was LDS-issue-bound (~160us for Q alone).
// Same verified tile scheme as final_mfma (R4): wave = 16 rows, 16 col-tiles,
// CIN/32 k-steps. OMODE: 0 = f32 [row][DM]; 1 = bf16 [row][DM];
// 2 = bf16 V^T [b][h][dk][s]. ACT: 1 = sigmoid.
// ---------------------------------------------------------------------------
template<int CIN, int OMODE, int ACT>
__global__ __launch_bounds__(256, 2) void proj_mfma_kernel(
    const ushort* __restrict__ Xb, const ushort* __restrict__ Wb, void* Yv) {
  const int tid = threadIdx.x;
  const int wave = tid >> 6, lane = tid & 63;
  const int q15 = lane & 15, quad = lane >> 4;
  const int row0 = blockIdx.x * 64 + wave * 16;
  constexpr int KS = CIN / 32;

  f32x4 acc[16];
#pragma unroll
  for (int t = 0; t < 16; ++t) acc[t] = (f32x4){0.f, 0.f, 0.f, 0.f};

  const ushort* abase = Xb + (size_t)(row0 + q15) * CIN + quad * 8;
  const ushort* bbase = Wb + (size_t)q15 * CIN + quad * 8;
#pragma unroll 2
  for (int ks = 0; ks < KS; ++ks) {
    bf16x8 af = ldbf8(abase + ks * 32);
#pragma unroll
    for (int t = 0; t < 16; ++t) {
      bf16x8 bf = ldbf8(bbase + (size_t)t * 16 * CIN + ks * 32);
      acc[t] = __builtin_amdgcn_mfma_f32_16x16x32_bf16(af, bf, acc[t], 0, 0, 0);
    }
  }
  // C[m=quad*4+reg][n=t*16+q15]
#pragma unroll
  for (int reg = 0; reg < 4; ++reg) {
    const int row = row0 + quad * 4 + reg;
#pragma unroll
    for (int t = 0; t < 16; ++t) {
      int col = t * 16 + q15;
      float v = acc[t][reg];
      if (ACT == 1) v = 1.f / (1.f + __expf(-v));
      if (OMODE == 0) {
        ((float*)Yv)[(size_t)row * DM + col] = v;
      } else if (OMODE == 1) {
        ((ushort*)Yv)[(size_t)row * DM + col] = f2bf(v);
      } else {
        int b_ = row >> 9, s = row & 511;
        int h = t >> 1, dk = (t & 1) * 16 + q15;
        ((ushort*)Yv)[((size_t)((b_ * NH + h) * DK + dk)) * MN + s] = f2bf(v);
      }
    }
  }
}

// ---------------------------------------------------------------------------
// Multi-scale conv1d (K=3,5,7) — R4 reg-preloaded weights version.
// ---------------------------------------------------------------------------
template<int K, int KOFF, int RPB>
__device__ __forceinline__ void conv_scale(
    const float* __restrict__ wrow, float bias,
    const float (*xs)[VD], float* __restrict__ acc) {
#pragma unroll
  for (int r = 0; r < RPB; ++r) acc[r] = bias;
#pragma unroll 2
  for (int i0 = 0; i0 < VD; i0 += 4) {
    float4 wf[K];
#pragma unroll
    for (int j = 0; j < K; ++j) wf[j] = *(const float4*)(wrow + i0 * K + j * 4);
    const float* wv = (const float*)wf;
#pragma unroll
    for (int i = 0; i < 4; ++i)
#pragma unroll
      for (int k = 0; k < K; ++k) {
        float w1 = wv[i * K + k];
#pragma unroll
        for (int r = 0; r < RPB; ++r)
          acc[r] += xs[r + k + KOFF][i0 + i] * w1;
      }
  }
}

template<int RPB>
__global__ __launch_bounds__(192) void msconv_kernel(
    const float* __restrict__ xv,
    const float* __restrict__ w3, const float* __restrict__ b3,
    const float* __restrict__ w5, const float* __restrict__ b5,
    const float* __restrict__ w7, const float* __restrict__ b7,
    float* __restrict__ xm) {
  const int bb_ = blockIdx.x / (MN / RPB);
  const int s0  = (blockIdx.x % (MN / RPB)) * RPB;
  const int t = threadIdx.x;
  __shared__ float xs[RPB + 6][VD];
  for (int i = t; i < (RPB + 6) * VD; i += 192) {
    int r = i / VD, c = i % VD;
    int ss = s0 + r - 3;
    xs[r][c] = (ss >= 0 && ss < MN) ? xv[((size_t)bb_ * MN + ss) * VD + c] : 0.f;
  }
  __syncthreads();
  const int scale = t / VD, o = t % VD;
  float acc[RPB];
  if (scale == 0)
    conv_scale<3, 2, RPB>(w3 + (size_t)o * VD * 3, b3[o], xs, acc);
  else if (scale == 1)
    conv_scale<5, 1, RPB>(w5 + (size_t)o * VD * 5, b5[o], xs, acc);
  else
    conv_scale<7, 0, RPB>(w7 + (size_t)o * VD * 7, b7[o], xs, acc);
#pragma unroll
  for (int r = 0; r < RPB; ++r)
    xm[((size_t)bb_ * MN + s0 + r) * D3 + scale * VD + o] = acc[r];
}

// ---------------------------------------------------------------------------
// pos_sum[j, d] = sum_i emb[clip(j-i, -R, R) + R, d]
// ---------------------------------------------------------------------------
__global__ __launch_bounds__(D3) void possum_kernel(
    const float* __restrict__ emb, float* __restrict__ psum) {
  const int j = blockIdx.x, d = threadIdx.x;
  float acc = 0.f;
  for (int r = 0; r < NREL; ++r) {
    int v = r - RMAX;
    int cnt;
    if (r == 0)             cnt = max(0, MN - (j + RMAX));
    else if (r == NREL - 1) cnt = max(0, j - RMAX + 1);
    else                    cnt = (j - v >= 0 && j - v < MN) ? 1 : 0;
    acc += (float)cnt * emb[(size_t)r * D3 + d];
  }
  psum[(size_t)j * D3 + d] = acc;
}

// ---------------------------------------------------------------------------
// rel-pos-enc closed form (elementwise), output bf16 (feeds K/V proj only)
// ---------------------------------------------------------------------------
__global__ __launch_bounds__(D3) void pe_kernel(
    const float* __restrict__ xm, const float* __restrict__ psum,
    const float* __restrict__ emb, const float* __restrict__ dww,
    const float* __restrict__ dwb, ushort* __restrict__ xpe) {
  const int bb_ = blockIdx.x / MN, j = blockIdx.x % MN;
  const int d = threadIdx.x;
  const size_t base = ((size_t)bb_ * MN + j) * D3 + d;
  float xc = xm[base];
  float fC = xc + emb[(size_t)RMAX * D3 + d];
  float fL = (j > 0)      ? xm[base - D3] + emb[(size_t)(RMAX - 1) * D3 + d] : 0.f;
  float fR = (j < MN - 1) ? xm[base + D3] + emb[(size_t)(RMAX + 1) * D3 + d] : 0.f;
  float dc = fL * dww[d * 3 + 0] + fC * dww[d * 3 + 1] + fR * dww[d * 3 + 2] + dwb[d];
  xpe[base] = f2bf(xc + (psum[(size_t)j * D3 + d] - fC + dc) * (1.f / MN));
}

// ---------------------------------------------------------------------------
// MFMA flash attention (transposed-operand scheme, R2/R3). Output bf16.
// ---------------------------------------------------------------------------
#define PROW 136
__global__ __launch_bounds__(256, 1) void attn_mfma_kernel(
    const ushort* __restrict__ Qb, const ushort* __restrict__ Kb,
    const ushort* __restrict__ Vt, ushort* __restrict__ Ao) {
  const int blk = blockIdx.x;
  const int qc = blk & 15;
  const int h  = (blk >> 4) & 7;
  const int b_ = blk >> 7;
  const int tid = threadIdx.x;
  const int wave = tid >> 6, lane = tid & 63;
  const int q15 = lane & 15, quad = lane >> 4;
  const int q0 = qc * 64 + wave * 16;

  __shared__ ushort Plds[4][16][PROW];
  ushort* prow = &Plds[wave][q15][0];

  const bf16x8 qfrag = ldbf8(Qb + ((size_t)(b_ * L + q0 + q15)) * DM + h * DK + quad * 8);

  f32x4 o0 = {0.f, 0.f, 0.f, 0.f}, o1 = {0.f, 0.f, 0.f, 0.f};
  float mrun = -1e30f, lsum = 0.f;
  const float scale = 0.17677669529663687f;  // 1/sqrt(32)

  const ushort* kbase = Kb + ((size_t)(b_ * MN) + q15) * DM + h * DK + quad * 8;
  const ushort* vbase = Vt + ((size_t)((b_ * NH + h) * DK) + q15) * MN;

  for (int c = 0; c < 4; ++c) {
    const int kb0 = c * 128;
    f32x4 s[8];
#pragma unroll
    for (int t = 0; t < 8; ++t) {
      bf16x8 af = ldbf8(kbase + (size_t)(kb0 + t * 16) * DM);
      f32x4 z = {0.f, 0.f, 0.f, 0.f};
      s[t] = __builtin_amdgcn_mfma_f32_16x16x32_bf16(af, qfrag, z, 0, 0, 0);
    }
    float ml = -1e30f;
#pragma unroll
    for (int t = 0; t < 8; ++t)
#pragma unroll
      for (int r = 0; r < 4; ++r) { s[t][r] *= scale; ml = fmaxf(ml, s[t][r]); }
    ml = fmaxf(ml, __shfl_xor(ml, 16));
    ml = fmaxf(ml, __shfl_xor(ml, 32));
    float mnew = fmaxf(mrun, ml);
    float alpha = __expf(mrun - mnew);
    mrun = mnew;
    lsum *= alpha;
#pragma unroll
    for (int r = 0; r < 4; ++r) { o0[r] *= alpha; o1[r] *= alpha; }
#pragma unroll
    for (int t = 0; t < 8; ++t) {
      float p0 = __expf(s[t][0] - mrun), p1 = __expf(s[t][1] - mrun);
      float p2 = __expf(s[t][2] - mrun), p3 = __expf(s[t][3] - mrun);
      lsum += (p0 + p1) + (p2 + p3);
      ushort4 pk = make_ushort4(f2bf(p0), f2bf(p1), f2bf(p2), f2bf(p3));
      *(ushort4*)(prow + t * 16 + quad * 4) = pk;
    }
#pragma unroll
    for (int t2 = 0; t2 < 4; ++t2) {
      bf16x8 bfr = ldbf8(prow + t2 * 32 + quad * 8);
      bf16x8 av0 = ldbf8(vbase + (size_t)(kb0 + t2 * 32 + quad * 8));
      bf16x8 av1 = ldbf8(vbase + (size_t)16 * MN + (kb0 + t2 * 32 + quad * 8));
      o0 = __builtin_amdgcn_mfma_f32_16x16x32_bf16(av0, bfr, o0, 0, 0, 0);
      o1 = __builtin_amdgcn_mfma_f32_16x16x32_bf16(av1, bfr, o1, 0, 0, 0);
    }
  }
  lsum += __shfl_xor(lsum, 16);
  lsum += __shfl_xor(lsum, 32);
  float rinv = 1.f / lsum;
  ushort* obase = Ao + ((size_t)(b_ * L + q0 + q15)) * DM + h * DK + quad * 4;
  *(ushort4*)(obase)      = make_ushort4(f2bf(o0[0] * rinv), f2bf(o0[1] * rinv),
                                         f2bf(o0[2] * rinv), f2bf(o0[3] * rinv));
  *(ushort4*)(obase + 16) = make_ushort4(f2bf(o1[0] * rinv), f2bf(o1[1] * rinv),
                                         f2bf(o1[2] * rinv), f2bf(o1[3] * rinv));
}

// ---------------------------------------------------------------------------
// Final via MFMA: fc (bf16 MFMA) + Gamma gating + residual + LayerNorm (R4).
// ---------------------------------------------------------------------------
__global__ __launch_bounds__(256, 2) void final_mfma_kernel(
    const ushort* __restrict__ Ao, const ushort* __restrict__ fcwb,
    const float* __restrict__ fcb, const float* __restrict__ G,
    const float* __restrict__ Xs, const float* __restrict__ lnw,
    const float* __restrict__ lnb, float* __restrict__ out) {
  const int tid = threadIdx.x;
  const int wave = tid >> 6, lane = tid & 63;
  const int q15 = lane & 15, quad = lane >> 4;
  const int row0 = blockIdx.x * 64 + wave * 16;

  f32x4 acc[16];
#pragma unroll
  for (int t = 0; t < 16; ++t) acc[t] = (f32x4){0.f, 0.f, 0.f, 0.f};

  const ushort* abase = Ao + (size_t)(row0 + q15) * DM + quad * 8;
  const ushort* bbase = fcwb + (size_t)q15 * DM + quad * 8;
#pragma unroll 2
  for (int ks = 0; ks < 8; ++ks) {
    bf16x8 af = ldbf8(abase + ks * 32);
#pragma unroll
    for (int t = 0; t < 16; ++t) {
      bf16x8 bf = ldbf8(bbase + (size_t)t * 16 * DM + ks * 32);
      acc[t] = __builtin_amdgcn_mfma_f32_16x16x32_bf16(af, bf, acc[t], 0, 0, 0);
    }
  }

  // epilogue: C[m=quad*4+reg][n=t*16+q15]
#pragma unroll
  for (int reg = 0; reg < 4; ++reg) {
    const int grow = row0 + quad * 4 + reg;
    const int b_ = grow >> 10;
    const int gl = (grow & 1023) & 511;
    const float* gbase = G + ((size_t)b_ * MN + gl) * DM + q15;
    const float* xbase = Xs + (size_t)grow * SD + q15;
    float vv[16];
    float s1 = 0.f, s2 = 0.f;
#pragma unroll
    for (int t = 0; t < 16; ++t) {
      int col = t * 16 + q15;
      float fcv = acc[t][reg] + fcb[col];
      float v = xbase[t * 16] + gbase[t * 16] * fcv;
      vv[t] = v; s1 += v; s2 += v * v;
    }
    s1 += __shfl_xor(s1, 1); s2 += __shfl_xor(s2, 1);
    s1 += __shfl_xor(s1, 2); s2 += __shfl_xor(s2, 2);
    s1 += __shfl_xor(s1, 4); s2 += __shfl_xor(s2, 4);
    s1 += __shfl_xor(s1, 8); s2 += __shfl_xor(s2, 8);
    float mu = s1 * (1.f / DM);
    float var = s2 * (1.f / DM) - mu * mu;
    float rs = rsqrtf(var + 1e-5f);
    float* obase = out + (size_t)grow * DM + q15;
#pragma unroll
    for (int t = 0; t < 16; ++t) {
      int col = t * 16 + q15;
      obase[t * 16] = (vv[t] - mu) * rs * lnw[col] + lnb[col];
    }
  }
}

// ---------------------------------------------------------------------------
extern "C" void kernel_launch(void* const* d_in, const int* in_sizes, int n_in,
                              void* d_out, int out_size, void* d_ws, size_t ws_size,
                              hipStream_t stream) {
  const float* x_spatial  = (const float*)d_in[0];
  const float* x_velocity = (const float*)d_in[1];
  const float* Wg   = (const float*)d_in[2];
  const float* w3   = (const float*)d_in[3];
  const float* b3   = (const float*)d_in[4];
  const float* w5   = (const float*)d_in[5];
  const float* b5   = (const float*)d_in[6];
  const float* w7   = (const float*)d_in[7];
  const float* b7   = (const float*)d_in[8];
  const float* remb = (const float*)d_in[9];
  const float* dww  = (const float*)d_in[10];
  const float* dwb  = (const float*)d_in[11];
  const float* Wq   = (const float*)d_in[12];
  const float* Wk   = (const float*)d_in[13];
  const float* Wv   = (const float*)d_in[14];
  const float* fcw  = (const float*)d_in[15];
  const float* fcb  = (const float*)d_in[16];
  const float* lnw  = (const float*)d_in[17];
  const float* lnb  = (const float*)d_in[18];
  float* out = (float*)d_out;

  char* w8 = (char*)d_ws;
  float*  Gamma = (float*)(w8);                     // 16,777,216
  float*  xm    = (float*)(w8 + 16777216);          // 12,582,912
  float*  psum  = (float*)(w8 + 29360128);          //    393,216
  ushort* xpeb  = (ushort*)(w8 + 29753344);         //  6,291,456 (bf16)
  ushort* Qb    = (ushort*)(w8 + 36044800);         // 16,777,216 (bf16)
  ushort* Kp    = (ushort*)(w8 + 52822016);         //  8,388,608 (bf16)
  ushort* Vt    = (ushort*)(w8 + 61210624);         //  8,388,608 (bf16, [b][h][dk][s])
  ushort* Ao    = (ushort*)(w8 + 69599232);         // 16,777,216 (bf16)
  ushort* fcwb  = (ushort*)(w8 + 86376448);         //    131,072 (bf16)
  ushort* xsb   = (ushort*)(w8 + 86507520);         // 16,777,216 (bf16)
  ushort* xvb   = (ushort*)(w8 + 103284736);        //  2,097,152 (bf16)
  ushort* Wgb   = (ushort*)(w8 + 105381888);        //     32,768 (bf16)
  ushort* Wqb   = (ushort*)(w8 + 105414656);        //    131,072 (bf16)
  ushort* Wkb   = (ushort*)(w8 + 105545728);        //     98,304 (bf16)
  ushort* Wvb   = (ushort*)(w8 + 105644032);        //     98,304 (bf16)
  // total 105,742,336 bytes

  // bf16 conversions
  tobf_kernel<<<(B * MN * VD) / 1024, 256, 0, stream>>>(x_velocity, xvb);
  tobf_kernel<<<(B * L * SD) / 1024, 256, 0, stream>>>(x_spatial, xsb);
  tobf_kernel<<<(DM * VD) / 1024, 256, 0, stream>>>(Wg, Wgb);
  tobf_kernel<<<(DM * SD) / 1024, 256, 0, stream>>>(Wq, Wqb);
  tobf_kernel<<<(DM * D3) / 1024, 256, 0, stream>>>(Wk, Wkb);
  tobf_kernel<<<(DM * D3) / 1024, 256, 0, stream>>>(Wv, Wvb);
  tobf_kernel<<<(DM * DM) / 1024, 256, 0, stream>>>(fcw, fcwb);

  msconv_kernel<8><<<B * MN / 8, 192, 0, stream>>>(x_velocity, w3, b3, w5, b5, w7, b7, xm);
  possum_kernel<<<MN, D3, 0, stream>>>(remb, psum);
  pe_kernel<<<B * MN, D3, 0, stream>>>(xm, psum, remb, dww, dwb, xpeb);

  proj_mfma_kernel<VD, 0, 1><<<B * MN / 64, 256, 0, stream>>>(xvb, Wgb, Gamma);
  proj_mfma_kernel<SD, 1, 0><<<B * L / 64, 256, 0, stream>>>(xsb, Wqb, Qb);
  proj_mfma_kernel<D3, 1, 0><<<B * MN / 64, 256, 0, stream>>>(xpeb, Wkb, Kp);
  proj_mfma_kernel<D3, 2, 0><<<B * MN / 64, 256, 0, stream>>>(xpeb, Wvb, Vt);

  attn_mfma_kernel<<<B * NH * (L / 64), 256, 0, stream>>>(Qb, Kp, Vt, Ao);
  final_mfma_kernel<<<B * L / 64, 256, 0, stream>>>(Ao, fcwb, fcb, Gamma,
                                                    x_spatial, lnw, lnb, out);
}

// Round 7
// 482.884 us; speedup vs baseline: 3.3056x; 1.0102x over previous
//
#include <hip/hip_runtime.h>

#define B   32
#define L   1024
#define MN  512
#define SD  256
#define VD  64
#define DM  256
#define D3  192
#define NH  8
#define DK  32
#define RMAX 30
#define NREL 61

typedef __attribute__((ext_vector_type(8))) __bf16 bf16x8;
typedef __attribute__((ext_vector_type(4))) float  f32x4;

static __device__ __forceinline__ ushort f2bf(float f) {
  unsigned u = __float_as_uint(f);
  unsigned r = (u + 0x7FFFu + ((u >> 16) & 1u)) >> 16;
  return (ushort)r;
}
static __device__ __forceinline__ bf16x8 ldbf8(const ushort* p) {
  return __builtin_bit_cast(bf16x8, *(const uint4*)p);
}

// ---------------------------------------------------------------------------
// f32 -> bf16 bulk convert. size must be multiple of 1024.
// ---------------------------------------------------------------------------
__global__ __launch_bounds__(256) void tobf_kernel(
    const float* __restrict__ src, ushort* __restrict__ dst) {
  int i = (blockIdx.x * 256 + threadIdx.x) * 4;
  float4 v = *(const float4*)(src + i);
  *(ushort4*)(dst + i) = make_ushort4(f2bf(v.x), f2bf(v.y), f2bf(v.z), f2bf(v.w));
}

// ---------------------------------------------------------------------------
// MFMA projection (R5): wave = 16 rows, 16 col-tiles, CIN/32 k-steps.
// OMODE: 0 = f32 [row][DM]; 1 = bf16 [row][DM]; 2 = bf16 V^T [b][h][dk][s].
// ---------------------------------------------------------------------------
template<int CIN, int OMODE, int ACT>
__global__ __launch_bounds__(256, 2) void proj_mfma_kernel(
    const ushort* __restrict__ Xb, const ushort* __restrict__ Wb, void* Yv) {
  const int tid = threadIdx.x;
  const int wave = tid >> 6, lane = tid & 63;
  const int q15 = lane & 15, quad = lane >> 4;
  const int row0 = blockIdx.x * 64 + wave * 16;
  constexpr int KS = CIN / 32;

  f32x4 acc[16];
#pragma unroll
  for (int t = 0; t < 16; ++t) acc[t] = (f32x4){0.f, 0.f, 0.f, 0.f};

  const ushort* abase = Xb + (size_t)(row0 + q15) * CIN + quad * 8;
  const ushort* bbase = Wb + (size_t)q15 * CIN + quad * 8;
#pragma unroll 2
  for (int ks = 0; ks < KS; ++ks) {
    bf16x8 af = ldbf8(abase + ks * 32);
#pragma unroll
    for (int t = 0; t < 16; ++t) {
      bf16x8 bf = ldbf8(bbase + (size_t)t * 16 * CIN + ks * 32);
      acc[t] = __builtin_amdgcn_mfma_f32_16x16x32_bf16(af, bf, acc[t], 0, 0, 0);
    }
  }
#pragma unroll
  for (int reg = 0; reg < 4; ++reg) {
    const int row = row0 + quad * 4 + reg;
#pragma unroll
    for (int t = 0; t < 16; ++t) {
      int col = t * 16 + q15;
      float v = acc[t][reg];
      if (ACT == 1) v = 1.f / (1.f + __expf(-v));
      if (OMODE == 0) {
        ((float*)Yv)[(size_t)row * DM + col] = v;
      } else if (OMODE == 1) {
        ((ushort*)Yv)[(size_t)row * DM + col] = f2bf(v);
      } else {
        int b_ = row >> 9, s = row & 511;
        int h = t >> 1, dk = (t & 1) * 16 + q15;
        ((ushort*)Yv)[((size_t)((b_ * NH + h) * DK + dk)) * MN + s] = f2bf(v);
      }
    }
  }
}

// ---------------------------------------------------------------------------
// Multi-scale conv1d (K=3,5,7) — R4 reg-preloaded weights version.
// ---------------------------------------------------------------------------
template<int K, int KOFF, int RPB>
__device__ __forceinline__ void conv_scale(
    const float* __restrict__ wrow, float bias,
    const float (*xs)[VD], float* __restrict__ acc) {
#pragma unroll
  for (int r = 0; r < RPB; ++r) acc[r] = bias;
#pragma unroll 2
  for (int i0 = 0; i0 < VD; i0 += 4) {
    float4 wf[K];
#pragma unroll
    for (int j = 0; j < K; ++j) wf[j] = *(const float4*)(wrow + i0 * K + j * 4);
    const float* wv = (const float*)wf;
#pragma unroll
    for (int i = 0; i < 4; ++i)
#pragma unroll
      for (int k = 0; k < K; ++k) {
        float w1 = wv[i * K + k];
#pragma unroll
        for (int r = 0; r < RPB; ++r)
          acc[r] += xs[r + k + KOFF][i0 + i] * w1;
      }
  }
}

template<int RPB>
__global__ __launch_bounds__(192) void msconv_kernel(
    const float* __restrict__ xv,
    const float* __restrict__ w3, const float* __restrict__ b3,
    const float* __restrict__ w5, const float* __restrict__ b5,
    const float* __restrict__ w7, const float* __restrict__ b7,
    float* __restrict__ xm) {
  const int bb_ = blockIdx.x / (MN / RPB);
  const int s0  = (blockIdx.x % (MN / RPB)) * RPB;
  const int t = threadIdx.x;
  __shared__ float xs[RPB + 6][VD];
  for (int i = t; i < (RPB + 6) * VD; i += 192) {
    int r = i / VD, c = i % VD;
    int ss = s0 + r - 3;
    xs[r][c] = (ss >= 0 && ss < MN) ? xv[((size_t)bb_ * MN + ss) * VD + c] : 0.f;
  }
  __syncthreads();
  const int scale = t / VD, o = t % VD;
  float acc[RPB];
  if (scale == 0)
    conv_scale<3, 2, RPB>(w3 + (size_t)o * VD * 3, b3[o], xs, acc);
  else if (scale == 1)
    conv_scale<5, 1, RPB>(w5 + (size_t)o * VD * 5, b5[o], xs, acc);
  else
    conv_scale<7, 0, RPB>(w7 + (size_t)o * VD * 7, b7[o], xs, acc);
#pragma unroll
  for (int r = 0; r < RPB; ++r)
    xm[((size_t)bb_ * MN + s0 + r) * D3 + scale * VD + o] = acc[r];
}

// ---------------------------------------------------------------------------
// pos_sum[j, d] = sum_i emb[clip(j-i, -R, R) + R, d]
// ---------------------------------------------------------------------------
__global__ __launch_bounds__(D3) void possum_kernel(
    const float* __restrict__ emb, float* __restrict__ psum) {
  const int j = blockIdx.x, d = threadIdx.x;
  float acc = 0.f;
  for (int r = 0; r < NREL; ++r) {
    int v = r - RMAX;
    int cnt;
    if (r == 0)             cnt = max(0, MN - (j + RMAX));
    else if (r == NREL - 1) cnt = max(0, j - RMAX + 1);
    else                    cnt = (j - v >= 0 && j - v < MN) ? 1 : 0;
    acc += (float)cnt * emb[(size_t)r * D3 + d];
  }
  psum[(size_t)j * D3 + d] = acc;
}

// ---------------------------------------------------------------------------
// rel-pos-enc closed form (elementwise), output bf16 (feeds K/V proj only)
// ---------------------------------------------------------------------------
__global__ __launch_bounds__(D3) void pe_kernel(
    const float* __restrict__ xm, const float* __restrict__ psum,
    const float* __restrict__ emb, const float* __restrict__ dww,
    const float* __restrict__ dwb, ushort* __restrict__ xpe) {
  const int bb_ = blockIdx.x / MN, j = blockIdx.x % MN;
  const int d = threadIdx.x;
  const size_t base = ((size_t)bb_ * MN + j) * D3 + d;
  float xc = xm[base];
  float fC = xc + emb[(size_t)RMAX * D3 + d];
  float fL = (j > 0)      ? xm[base - D3] + emb[(size_t)(RMAX - 1) * D3 + d] : 0.f;
  float fR = (j < MN - 1) ? xm[base + D3] + emb[(size_t)(RMAX + 1) * D3 + d] : 0.f;
  float dc = fL * dww[d * 3 + 0] + fC * dww[d * 3 + 1] + fR * dww[d * 3 + 2] + dwb[d];
  xpe[base] = f2bf(xc + (psum[(size_t)j * D3 + d] - fC + dc) * (1.f / MN));
}

// ---------------------------------------------------------------------------
// MFMA flash attention (transposed-operand scheme, R2).
// R6 post-mortem: 17.4 KB P-LDS + exposed V-load latency + RNE pack VALU made
// it overhead-bound (MfmaUtil 5%). R7: (1) P staged per 32-key group -> LDS
// 4.6 KB total; (2) all 8 V frags prefetched at c-iter top with the K loads;
// (3) P packed by truncation via v_perm_b32 (1 instr/pair; f32 lsum keeps the
// normalization exact). launch_bounds(256,4): ~105 VGPR < 128 cap, no spill.
// ---------------------------------------------------------------------------
#define PSTRIDE 36  // ushorts per q-row (32 keys + pad)
__global__ __launch_bounds__(256, 4) void attn_mfma_kernel(
    const ushort* __restrict__ Qb, const ushort* __restrict__ Kb,
    const ushort* __restrict__ Vt, ushort* __restrict__ Ao) {
  const int blk = blockIdx.x;
  const int qc = blk & 15;
  const int h  = (blk >> 4) & 7;
  const int b_ = blk >> 7;
  const int tid = threadIdx.x;
  const int wave = tid >> 6, lane = tid & 63;
  const int q15 = lane & 15, quad = lane >> 4;
  const int q0 = qc * 64 + wave * 16;

  __shared__ ushort Plds[4][16][PSTRIDE];   // per-wave 16q x 32key staging
  ushort* prow = &Plds[wave][q15][0];

  const bf16x8 qfrag = ldbf8(Qb + ((size_t)(b_ * L + q0 + q15)) * DM + h * DK + quad * 8);

  f32x4 o0 = {0.f, 0.f, 0.f, 0.f}, o1 = {0.f, 0.f, 0.f, 0.f};
  float mrun = -1e30f, lsum = 0.f;
  const float scale = 0.17677669529663687f;  // 1/sqrt(32)

  const ushort* kbase = Kb + ((size_t)(b_ * MN) + q15) * DM + h * DK + quad * 8;
  const ushort* vbase = Vt + ((size_t)((b_ * NH + h) * DK) + q15) * MN;

  for (int c = 0; c < 4; ++c) {
    const int kb0 = c * 128;
    // prefetch all V fragments for this c-iter (independent of softmax)
    bf16x8 av[8];
#pragma unroll
    for (int g = 0; g < 4; ++g) {
      av[g * 2]     = ldbf8(vbase + (size_t)(kb0 + g * 32 + quad * 8));
      av[g * 2 + 1] = ldbf8(vbase + (size_t)16 * MN + (kb0 + g * 32 + quad * 8));
    }
    f32x4 s[8];
#pragma unroll
    for (int t = 0; t < 8; ++t) {
      bf16x8 af = ldbf8(kbase + (size_t)(kb0 + t * 16) * DM);
      f32x4 z = {0.f, 0.f, 0.f, 0.f};
      s[t] = __builtin_amdgcn_mfma_f32_16x16x32_bf16(af, qfrag, z, 0, 0, 0);
    }
    float ml = -1e30f;
#pragma unroll
    for (int t = 0; t < 8; ++t)
#pragma unroll
      for (int r = 0; r < 4; ++r) { s[t][r] *= scale; ml = fmaxf(ml, s[t][r]); }
    ml = fmaxf(ml, __shfl_xor(ml, 16));
    ml = fmaxf(ml, __shfl_xor(ml, 32));
    float mnew = fmaxf(mrun, ml);
    float alpha = __expf(mrun - mnew);
    mrun = mnew;
    lsum *= alpha;
#pragma unroll
    for (int r = 0; r < 4; ++r) { o0[r] *= alpha; o1[r] *= alpha; }
    // per 32-key group: exp -> pack(trunc) -> tiny LDS round-trip -> PV mfma
#pragma unroll
    for (int g = 0; g < 4; ++g) {
#pragma unroll
      for (int tp = 0; tp < 2; ++tp) {
        int t = 2 * g + tp;
        float p0 = __expf(s[t][0] - mrun), p1 = __expf(s[t][1] - mrun);
        float p2 = __expf(s[t][2] - mrun), p3 = __expf(s[t][3] - mrun);
        lsum += (p0 + p1) + (p2 + p3);
        uint u01 = __builtin_amdgcn_perm(__float_as_uint(p1), __float_as_uint(p0), 0x07060302u);
        uint u23 = __builtin_amdgcn_perm(__float_as_uint(p3), __float_as_uint(p2), 0x07060302u);
        *(uint2*)(prow + tp * 16 + quad * 4) = make_uint2(u01, u23);
      }
      bf16x8 bfr = ldbf8(prow + quad * 8);   // B[k=key_local][n=q]
      o0 = __builtin_amdgcn_mfma_f32_16x16x32_bf16(av[g * 2],     bfr, o0, 0, 0, 0);
      o1 = __builtin_amdgcn_mfma_f32_16x16x32_bf16(av[g * 2 + 1], bfr, o1, 0, 0, 0);
    }
  }
  lsum += __shfl_xor(lsum, 16);
  lsum += __shfl_xor(lsum, 32);
  float rinv = 1.f / lsum;
  ushort* obase = Ao + ((size_t)(b_ * L + q0 + q15)) * DM + h * DK + quad * 4;
  *(ushort4*)(obase)      = make_ushort4(f2bf(o0[0] * rinv), f2bf(o0[1] * rinv),
                                         f2bf(o0[2] * rinv), f2bf(o0[3] * rinv));
  *(ushort4*)(obase + 16) = make_ushort4(f2bf(o1[0] * rinv), f2bf(o1[1] * rinv),
                                         f2bf(o1[2] * rinv), f2bf(o1[3] * rinv));
}

// ---------------------------------------------------------------------------
// Final via MFMA: fc (bf16 MFMA) + Gamma gating + residual + LayerNorm (R4).
// ---------------------------------------------------------------------------
__global__ __launch_bounds__(256, 2) void final_mfma_kernel(
    const ushort* __restrict__ Ao, const ushort* __restrict__ fcwb,
    const float* __restrict__ fcb, const float* __restrict__ G,
    const float* __restrict__ Xs, const float* __restrict__ lnw,
    const float* __restrict__ lnb, float* __restrict__ out) {
  const int tid = threadIdx.x;
  const int wave = tid >> 6, lane = tid & 63;
  const int q15 = lane & 15, quad = lane >> 4;
  const int row0 = blockIdx.x * 64 + wave * 16;

  f32x4 acc[16];
#pragma unroll
  for (int t = 0; t < 16; ++t) acc[t] = (f32x4){0.f, 0.f, 0.f, 0.f};

  const ushort* abase = Ao + (size_t)(row0 + q15) * DM + quad * 8;
  const ushort* bbase = fcwb + (size_t)q15 * DM + quad * 8;
#pragma unroll 2
  for (int ks = 0; ks < 8; ++ks) {
    bf16x8 af = ldbf8(abase + ks * 32);
#pragma unroll
    for (int t = 0; t < 16; ++t) {
      bf16x8 bf = ldbf8(bbase + (size_t)t * 16 * DM + ks * 32);
      acc[t] = __builtin_amdgcn_mfma_f32_16x16x32_bf16(af, bf, acc[t], 0, 0, 0);
    }
  }
#pragma unroll
  for (int reg = 0; reg < 4; ++reg) {
    const int grow = row0 + quad * 4 + reg;
    const int b_ = grow >> 10;
    const int gl = (grow & 1023) & 511;
    const float* gbase = G + ((size_t)b_ * MN + gl) * DM + q15;
    const float* xbase = Xs + (size_t)grow * SD + q15;
    float vv[16];
    float s1 = 0.f, s2 = 0.f;
#pragma unroll
    for (int t = 0; t < 16; ++t) {
      int col = t * 16 + q15;
      float fcv = acc[t][reg] + fcb[col];
      float v = xbase[t * 16] + gbase[t * 16] * fcv;
      vv[t] = v; s1 += v; s2 += v * v;
    }
    s1 += __shfl_xor(s1, 1); s2 += __shfl_xor(s2, 1);
    s1 += __shfl_xor(s1, 2); s2 += __shfl_xor(s2, 2);
    s1 += __shfl_xor(s1, 4); s2 += __shfl_xor(s2, 4);
    s1 += __shfl_xor(s1, 8); s2 += __shfl_xor(s2, 8);
    float mu = s1 * (1.f / DM);
    float var = s2 * (1.f / DM) - mu * mu;
    float rs = rsqrtf(var + 1e-5f);
    float* obase = out + (size_t)grow * DM + q15;
#pragma unroll
    for (int t = 0; t < 16; ++t) {
      int col = t * 16 + q15;
      obase[t * 16] = (vv[t] - mu) * rs * lnw[col] + lnb[col];
    }
  }
}

// ---------------------------------------------------------------------------
extern "C" void kernel_launch(void* const* d_in, const int* in_sizes, int n_in,
                              void* d_out, int out_size, void* d_ws, size_t ws_size,
                              hipStream_t stream) {
  const float* x_spatial  = (const float*)d_in[0];
  const float* x_velocity = (const float*)d_in[1];
  const float* Wg   = (const float*)d_in[2];
  const float* w3   = (const float*)d_in[3];
  const float* b3   = (const float*)d_in[4];
  const float* w5   = (const float*)d_in[5];
  const float* b5   = (const float*)d_in[6];
  const float* w7   = (const float*)d_in[7];
  const float* b7   = (const float*)d_in[8];
  const float* remb = (const float*)d_in[9];
  const float* dww  = (const float*)d_in[10];
  const float* dwb  = (const float*)d_in[11];
  const float* Wq   = (const float*)d_in[12];
  const float* Wk   = (const float*)d_in[13];
  const float* Wv   = (const float*)d_in[14];
  const float* fcw  = (const float*)d_in[15];
  const float* fcb  = (const float*)d_in[16];
  const float* lnw  = (const float*)d_in[17];
  const float* lnb  = (const float*)d_in[18];
  float* out = (float*)d_out;

  char* w8 = (char*)d_ws;
  float*  Gamma = (float*)(w8);                     // 16,777,216
  float*  xm    = (float*)(w8 + 16777216);          // 12,582,912
  float*  psum  = (float*)(w8 + 29360128);          //    393,216
  ushort* xpeb  = (ushort*)(w8 + 29753344);         //  6,291,456 (bf16)
  ushort* Qb    = (ushort*)(w8 + 36044800);         // 16,777,216 (bf16)
  ushort* Kp    = (ushort*)(w8 + 52822016);         //  8,388,608 (bf16)
  ushort* Vt    = (ushort*)(w8 + 61210624);         //  8,388,608 (bf16, [b][h][dk][s])
  ushort* Ao    = (ushort*)(w8 + 69599232);         // 16,777,216 (bf16)
  ushort* fcwb  = (ushort*)(w8 + 86376448);         //    131,072 (bf16)
  ushort* xsb   = (ushort*)(w8 + 86507520);         // 16,777,216 (bf16)
  ushort* xvb   = (ushort*)(w8 + 103284736);        //  2,097,152 (bf16)
  ushort* Wgb   = (ushort*)(w8 + 105381888);        //     32,768 (bf16)
  ushort* Wqb   = (ushort*)(w8 + 105414656);        //    131,072 (bf16)
  ushort* Wkb   = (ushort*)(w8 + 105545728);        //     98,304 (bf16)
  ushort* Wvb   = (ushort*)(w8 + 105644032);        //     98,304 (bf16)

  tobf_kernel<<<(B * MN * VD) / 1024, 256, 0, stream>>>(x_velocity, xvb);
  tobf_kernel<<<(B * L * SD) / 1024, 256, 0, stream>>>(x_spatial, xsb);
  tobf_kernel<<<(DM * VD) / 1024, 256, 0, stream>>>(Wg, Wgb);
  tobf_kernel<<<(DM * SD) / 1024, 256, 0, stream>>>(Wq, Wqb);
  tobf_kernel<<<(DM * D3) / 1024, 256, 0, stream>>>(Wk, Wkb);
  tobf_kernel<<<(DM * D3) / 1024, 256, 0, stream>>>(Wv, Wvb);
  tobf_kernel<<<(DM * DM) / 1024, 256, 0, stream>>>(fcw, fcwb);

  msconv_kernel<8><<<B * MN / 8, 192, 0, stream>>>(x_velocity, w3, b3, w5, b5, w7, b7, xm);
  possum_kernel<<<MN, D3, 0, stream>>>(remb, psum);
  pe_kernel<<<B * MN, D3, 0, stream>>>(xm, psum, remb, dww, dwb, xpeb);

  proj_mfma_kernel<VD, 0, 1><<<B * MN / 64, 256, 0, stream>>>(xvb, Wgb, Gamma);
  proj_mfma_kernel<SD, 1, 0><<<B * L / 64, 256, 0, stream>>>(xsb, Wqb, Qb);
  proj_mfma_kernel<D3, 1, 0><<<B * MN / 64, 256, 0, stream>>>(xpeb, Wkb, Kp);
  proj_mfma_kernel<D3, 2, 0><<<B * MN / 64, 256, 0, stream>>>(xpeb, Wvb, Vt);

  attn_mfma_kernel<<<B * NH * (L / 64), 256, 0, stream>>>(Qb, Kp, Vt, Ao);
  final_mfma_kernel<<<B * L / 64, 256, 0, stream>>>(Ao, fcwb, fcb, Gamma,
                                                    x_spatial, lnw, lnb, out);
}

// Round 8
// 454.958 us; speedup vs baseline: 3.5085x; 1.0614x over previous
//
#include <hip/hip_runtime.h>

#define B   32
#define L   1024
#define MN  512
#define SD  256
#define VD  64
#define DM  256
#define D3  192
#define NH  8
#define DK  32
#define RMAX 30
#define NREL 61

typedef __attribute__((ext_vector_type(8))) __bf16 bf16x8;
typedef __attribute__((ext_vector_type(4))) float  f32x4;

static __device__ __forceinline__ ushort f2bf(float f) {
  unsigned u = __float_as_uint(f);
  unsigned r = (u + 0x7FFFu + ((u >> 16) & 1u)) >> 16;
  return (ushort)r;
}
static __device__ __forceinline__ bf16x8 ldbf8(const ushort* p) {
  return __builtin_bit_cast(bf16x8, *(const uint4*)p);
}

// ---------------------------------------------------------------------------
// f32 -> bf16 bulk convert. size must be multiple of 1024.
// ---------------------------------------------------------------------------
__global__ __launch_bounds__(256) void tobf_kernel(
    const float* __restrict__ src, ushort* __restrict__ dst) {
  int i = (blockIdx.x * 256 + threadIdx.x) * 4;
  float4 v = *(const float4*)(src + i);
  *(ushort4*)(dst + i) = make_ushort4(f2bf(v.x), f2bf(v.y), f2bf(v.z), f2bf(v.w));
}

// ---------------------------------------------------------------------------
// MFMA projection (R5): wave = 16 rows, 16 col-tiles, CIN/32 k-steps.
// OMODE: 0 = f32 [row][DM]; 1 = bf16 [row][DM]; 2 = bf16 V^T [b][h][dk][s];
//        3 = bf16 K [b][h][s][dk]  (R8: coalesced K-fragment rows)
// ---------------------------------------------------------------------------
template<int CIN, int OMODE, int ACT>
__global__ __launch_bounds__(256, 2) void proj_mfma_kernel(
    const ushort* __restrict__ Xb, const ushort* __restrict__ Wb, void* Yv) {
  const int tid = threadIdx.x;
  const int wave = tid >> 6, lane = tid & 63;
  const int q15 = lane & 15, quad = lane >> 4;
  const int row0 = blockIdx.x * 64 + wave * 16;
  constexpr int KS = CIN / 32;

  f32x4 acc[16];
#pragma unroll
  for (int t = 0; t < 16; ++t) acc[t] = (f32x4){0.f, 0.f, 0.f, 0.f};

  const ushort* abase = Xb + (size_t)(row0 + q15) * CIN + quad * 8;
  const ushort* bbase = Wb + (size_t)q15 * CIN + quad * 8;
#pragma unroll 2
  for (int ks = 0; ks < KS; ++ks) {
    bf16x8 af = ldbf8(abase + ks * 32);
#pragma unroll
    for (int t = 0; t < 16; ++t) {
      bf16x8 bf = ldbf8(bbase + (size_t)t * 16 * CIN + ks * 32);
      acc[t] = __builtin_amdgcn_mfma_f32_16x16x32_bf16(af, bf, acc[t], 0, 0, 0);
    }
  }
#pragma unroll
  for (int reg = 0; reg < 4; ++reg) {
    const int row = row0 + quad * 4 + reg;
#pragma unroll
    for (int t = 0; t < 16; ++t) {
      int col = t * 16 + q15;
      float v = acc[t][reg];
      if (ACT == 1) v = 1.f / (1.f + __expf(-v));
      if (OMODE == 0) {
        ((float*)Yv)[(size_t)row * DM + col] = v;
      } else if (OMODE == 1) {
        ((ushort*)Yv)[(size_t)row * DM + col] = f2bf(v);
      } else if (OMODE == 2) {
        int b_ = row >> 9, s = row & 511;
        int h = t >> 1, dk = (t & 1) * 16 + q15;
        ((ushort*)Yv)[((size_t)((b_ * NH + h) * DK + dk)) * MN + s] = f2bf(v);
      } else {
        int b_ = row >> 9, s = row & 511;
        int h = col >> 5, dk = col & 31;
        ((ushort*)Yv)[((size_t)((b_ * NH + h) * MN + s)) * DK + dk] = f2bf(v);
      }
    }
  }
}

// ---------------------------------------------------------------------------
// Multi-scale conv1d (K=3,5,7) — R4 reg-preloaded weights version.
// ---------------------------------------------------------------------------
template<int K, int KOFF, int RPB>
__device__ __forceinline__ void conv_scale(
    const float* __restrict__ wrow, float bias,
    const float (*xs)[VD], float* __restrict__ acc) {
#pragma unroll
  for (int r = 0; r < RPB; ++r) acc[r] = bias;
#pragma unroll 2
  for (int i0 = 0; i0 < VD; i0 += 4) {
    float4 wf[K];
#pragma unroll
    for (int j = 0; j < K; ++j) wf[j] = *(const float4*)(wrow + i0 * K + j * 4);
    const float* wv = (const float*)wf;
#pragma unroll
    for (int i = 0; i < 4; ++i)
#pragma unroll
      for (int k = 0; k < K; ++k) {
        float w1 = wv[i * K + k];
#pragma unroll
        for (int r = 0; r < RPB; ++r)
          acc[r] += xs[r + k + KOFF][i0 + i] * w1;
      }
  }
}

template<int RPB>
__global__ __launch_bounds__(192) void msconv_kernel(
    const float* __restrict__ xv,
    const float* __restrict__ w3, const float* __restrict__ b3,
    const float* __restrict__ w5, const float* __restrict__ b5,
    const float* __restrict__ w7, const float* __restrict__ b7,
    float* __restrict__ xm) {
  const int bb_ = blockIdx.x / (MN / RPB);
  const int s0  = (blockIdx.x % (MN / RPB)) * RPB;
  const int t = threadIdx.x;
  __shared__ float xs[RPB + 6][VD];
  for (int i = t; i < (RPB + 6) * VD; i += 192) {
    int r = i / VD, c = i % VD;
    int ss = s0 + r - 3;
    xs[r][c] = (ss >= 0 && ss < MN) ? xv[((size_t)bb_ * MN + ss) * VD + c] : 0.f;
  }
  __syncthreads();
  const int scale = t / VD, o = t % VD;
  float acc[RPB];
  if (scale == 0)
    conv_scale<3, 2, RPB>(w3 + (size_t)o * VD * 3, b3[o], xs, acc);
  else if (scale == 1)
    conv_scale<5, 1, RPB>(w5 + (size_t)o * VD * 5, b5[o], xs, acc);
  else
    conv_scale<7, 0, RPB>(w7 + (size_t)o * VD * 7, b7[o], xs, acc);
#pragma unroll
  for (int r = 0; r < RPB; ++r)
    xm[((size_t)bb_ * MN + s0 + r) * D3 + scale * VD + o] = acc[r];
}

// ---------------------------------------------------------------------------
// pos_sum[j, d] = sum_i emb[clip(j-i, -R, R) + R, d]
// ---------------------------------------------------------------------------
__global__ __launch_bounds__(D3) void possum_kernel(
    const float* __restrict__ emb, float* __restrict__ psum) {
  const int j = blockIdx.x, d = threadIdx.x;
  float acc = 0.f;
  for (int r = 0; r < NREL; ++r) {
    int v = r - RMAX;
    int cnt;
    if (r == 0)             cnt = max(0, MN - (j + RMAX));
    else if (r == NREL - 1) cnt = max(0, j - RMAX + 1);
    else                    cnt = (j - v >= 0 && j - v < MN) ? 1 : 0;
    acc += (float)cnt * emb[(size_t)r * D3 + d];
  }
  psum[(size_t)j * D3 + d] = acc;
}

// ---------------------------------------------------------------------------
// rel-pos-enc closed form (elementwise), output bf16 (feeds K/V proj only)
// ---------------------------------------------------------------------------
__global__ __launch_bounds__(D3) void pe_kernel(
    const float* __restrict__ xm, const float* __restrict__ psum,
    const float* __restrict__ emb, const float* __restrict__ dww,
    const float* __restrict__ dwb, ushort* __restrict__ xpe) {
  const int bb_ = blockIdx.x / MN, j = blockIdx.x % MN;
  const int d = threadIdx.x;
  const size_t base = ((size_t)bb_ * MN + j) * D3 + d;
  float xc = xm[base];
  float fC = xc + emb[(size_t)RMAX * D3 + d];
  float fL = (j > 0)      ? xm[base - D3] + emb[(size_t)(RMAX - 1) * D3 + d] : 0.f;
  float fR = (j < MN - 1) ? xm[base + D3] + emb[(size_t)(RMAX + 1) * D3 + d] : 0.f;
  float dc = fL * dww[d * 3 + 0] + fC * dww[d * 3 + 1] + fR * dww[d * 3 + 2] + dwb[d];
  xpe[base] = f2bf(xc + (psum[(size_t)j * D3 + d] - fC + dc) * (1.f / MN));
}

// ---------------------------------------------------------------------------
// MFMA flash attention (transposed-operand scheme, R2/R7).
// R7 post-mortem: HBM-transaction-bound — FETCH 74MB vs 33.5 ideal. blk low
// bits were qc, so the 16 q-chunks sharing a (b,h)'s K/V landed on 16
// different XCDs (round-robin) -> per-XCD HBM re-fetch. R8:
// (1) blk = qc*256 + bh  => XCD = bh%8 = h; per-XCD K/V working set 2MB < L2.
// (2) K stored [b][h][s][dk] so each K A-frag load is one contiguous 1KB
//     segment (16 rows x 64B) instead of 16 scattered lines.
// ---------------------------------------------------------------------------
#define PSTRIDE 36  // ushorts per q-row (32 keys + pad)
__global__ __launch_bounds__(256, 4) void attn_mfma_kernel(
    const ushort* __restrict__ Qb, const ushort* __restrict__ Kb,
    const ushort* __restrict__ Vt, ushort* __restrict__ Ao) {
  const int blk = blockIdx.x;
  const int bh = blk & 255;        // low bits -> fixed XCD per (b,h)
  const int qc = blk >> 8;
  const int h  = bh & 7;
  const int b_ = bh >> 3;
  const int tid = threadIdx.x;
  const int wave = tid >> 6, lane = tid & 63;
  const int q15 = lane & 15, quad = lane >> 4;
  const int q0 = qc * 64 + wave * 16;

  __shared__ ushort Plds[4][16][PSTRIDE];   // per-wave 16q x 32key staging
  ushort* prow = &Plds[wave][q15][0];

  const bf16x8 qfrag = ldbf8(Qb + ((size_t)(b_ * L + q0 + q15)) * DM + h * DK + quad * 8);

  f32x4 o0 = {0.f, 0.f, 0.f, 0.f}, o1 = {0.f, 0.f, 0.f, 0.f};
  float mrun = -1e30f, lsum = 0.f;
  const float scale = 0.17677669529663687f;  // 1/sqrt(32)

  // K[b][h][s][dk]: lane reads row (key) q15-relative, 64B rows -> contiguous
  const ushort* kbase = Kb + (((size_t)(b_ * NH + h) * MN) + q15) * DK + quad * 8;
  const ushort* vbase = Vt + ((size_t)((b_ * NH + h) * DK) + q15) * MN;

  for (int c = 0; c < 4; ++c) {
    const int kb0 = c * 128;
    // prefetch all V fragments for this c-iter (independent of softmax)
    bf16x8 av[8];
#pragma unroll
    for (int g = 0; g < 4; ++g) {
      av[g * 2]     = ldbf8(vbase + (size_t)(kb0 + g * 32 + quad * 8));
      av[g * 2 + 1] = ldbf8(vbase + (size_t)16 * MN + (kb0 + g * 32 + quad * 8));
    }
    f32x4 s[8];
#pragma unroll
    for (int t = 0; t < 8; ++t) {
      bf16x8 af = ldbf8(kbase + (size_t)(kb0 + t * 16) * DK);
      f32x4 z = {0.f, 0.f, 0.f, 0.f};
      s[t] = __builtin_amdgcn_mfma_f32_16x16x32_bf16(af, qfrag, z, 0, 0, 0);
    }
    float ml = -1e30f;
#pragma unroll
    for (int t = 0; t < 8; ++t)
#pragma unroll
      for (int r = 0; r < 4; ++r) { s[t][r] *= scale; ml = fmaxf(ml, s[t][r]); }
    ml = fmaxf(ml, __shfl_xor(ml, 16));
    ml = fmaxf(ml, __shfl_xor(ml, 32));
    float mnew = fmaxf(mrun, ml);
    float alpha = __expf(mrun - mnew);
    mrun = mnew;
    lsum *= alpha;
#pragma unroll
    for (int r = 0; r < 4; ++r) { o0[r] *= alpha; o1[r] *= alpha; }
    // per 32-key group: exp -> pack(trunc) -> tiny LDS round-trip -> PV mfma
#pragma unroll
    for (int g = 0; g < 4; ++g) {
#pragma unroll
      for (int tp = 0; tp < 2; ++tp) {
        int t = 2 * g + tp;
        float p0 = __expf(s[t][0] - mrun), p1 = __expf(s[t][1] - mrun);
        float p2 = __expf(s[t][2] - mrun), p3 = __expf(s[t][3] - mrun);
        lsum += (p0 + p1) + (p2 + p3);
        uint u01 = __builtin_amdgcn_perm(__float_as_uint(p1), __float_as_uint(p0), 0x07060302u);
        uint u23 = __builtin_amdgcn_perm(__float_as_uint(p3), __float_as_uint(p2), 0x07060302u);
        *(uint2*)(prow + tp * 16 + quad * 4) = make_uint2(u01, u23);
      }
      bf16x8 bfr = ldbf8(prow + quad * 8);   // B[k=key_local][n=q]
      o0 = __builtin_amdgcn_mfma_f32_16x16x32_bf16(av[g * 2],     bfr, o0, 0, 0, 0);
      o1 = __builtin_amdgcn_mfma_f32_16x16x32_bf16(av[g * 2 + 1], bfr, o1, 0, 0, 0);
    }
  }
  lsum += __shfl_xor(lsum, 16);
  lsum += __shfl_xor(lsum, 32);
  float rinv = 1.f / lsum;
  ushort* obase = Ao + ((size_t)(b_ * L + q0 + q15)) * DM + h * DK + quad * 4;
  *(ushort4*)(obase)      = make_ushort4(f2bf(o0[0] * rinv), f2bf(o0[1] * rinv),
                                         f2bf(o0[2] * rinv), f2bf(o0[3] * rinv));
  *(ushort4*)(obase + 16) = make_ushort4(f2bf(o1[0] * rinv), f2bf(o1[1] * rinv),
                                         f2bf(o1[2] * rinv), f2bf(o1[3] * rinv));
}

// ---------------------------------------------------------------------------
// Final via MFMA: fc (bf16 MFMA) + Gamma gating + residual + LayerNorm (R4).
// ---------------------------------------------------------------------------
__global__ __launch_bounds__(256, 2) void final_mfma_kernel(
    const ushort* __restrict__ Ao, const ushort* __restrict__ fcwb,
    const float* __restrict__ fcb, const float* __restrict__ G,
    const float* __restrict__ Xs, const float* __restrict__ lnw,
    const float* __restrict__ lnb, float* __restrict__ out) {
  const int tid = threadIdx.x;
  const int wave = tid >> 6, lane = tid & 63;
  const int q15 = lane & 15, quad = lane >> 4;
  const int row0 = blockIdx.x * 64 + wave * 16;

  f32x4 acc[16];
#pragma unroll
  for (int t = 0; t < 16; ++t) acc[t] = (f32x4){0.f, 0.f, 0.f, 0.f};

  const ushort* abase = Ao + (size_t)(row0 + q15) * DM + quad * 8;
  const ushort* bbase = fcwb + (size_t)q15 * DM + quad * 8;
#pragma unroll 2
  for (int ks = 0; ks < 8; ++ks) {
    bf16x8 af = ldbf8(abase + ks * 32);
#pragma unroll
    for (int t = 0; t < 16; ++t) {
      bf16x8 bf = ldbf8(bbase + (size_t)t * 16 * DM + ks * 32);
      acc[t] = __builtin_amdgcn_mfma_f32_16x16x32_bf16(af, bf, acc[t], 0, 0, 0);
    }
  }
#pragma unroll
  for (int reg = 0; reg < 4; ++reg) {
    const int grow = row0 + quad * 4 + reg;
    const int b_ = grow >> 10;
    const int gl = (grow & 1023) & 511;
    const float* gbase = G + ((size_t)b_ * MN + gl) * DM + q15;
    const float* xbase = Xs + (size_t)grow * SD + q15;
    float vv[16];
    float s1 = 0.f, s2 = 0.f;
#pragma unroll
    for (int t = 0; t < 16; ++t) {
      int col = t * 16 + q15;
      float fcv = acc[t][reg] + fcb[col];
      float v = xbase[t * 16] + gbase[t * 16] * fcv;
      vv[t] = v; s1 += v; s2 += v * v;
    }
    s1 += __shfl_xor(s1, 1); s2 += __shfl_xor(s2, 1);
    s1 += __shfl_xor(s1, 2); s2 += __shfl_xor(s2, 2);
    s1 += __shfl_xor(s1, 4); s2 += __shfl_xor(s2, 4);
    s1 += __shfl_xor(s1, 8); s2 += __shfl_xor(s2, 8);
    float mu = s1 * (1.f / DM);
    float var = s2 * (1.f / DM) - mu * mu;
    float rs = rsqrtf(var + 1e-5f);
    float* obase = out + (size_t)grow * DM + q15;
#pragma unroll
    for (int t = 0; t < 16; ++t) {
      int col = t * 16 + q15;
      obase[t * 16] = (vv[t] - mu) * rs * lnw[col] + lnb[col];
    }
  }
}

// ---------------------------------------------------------------------------
extern "C" void kernel_launch(void* const* d_in, const int* in_sizes, int n_in,
                              void* d_out, int out_size, void* d_ws, size_t ws_size,
                              hipStream_t stream) {
  const float* x_spatial  = (const float*)d_in[0];
  const float* x_velocity = (const float*)d_in[1];
  const float* Wg   = (const float*)d_in[2];
  const float* w3   = (const float*)d_in[3];
  const float* b3   = (const float*)d_in[4];
  const float* w5   = (const float*)d_in[5];
  const float* b5   = (const float*)d_in[6];
  const float* w7   = (const float*)d_in[7];
  const float* b7   = (const float*)d_in[8];
  const float* remb = (const float*)d_in[9];
  const float* dww  = (const float*)d_in[10];
  const float* dwb  = (const float*)d_in[11];
  const float* Wq   = (const float*)d_in[12];
  const float* Wk   = (const float*)d_in[13];
  const float* Wv   = (const float*)d_in[14];
  const float* fcw  = (const float*)d_in[15];
  const float* fcb  = (const float*)d_in[16];
  const float* lnw  = (const float*)d_in[17];
  const float* lnb  = (const float*)d_in[18];
  float* out = (float*)d_out;

  char* w8 = (char*)d_ws;
  float*  Gamma = (float*)(w8);                     // 16,777,216
  float*  xm    = (float*)(w8 + 16777216);          // 12,582,912
  float*  psum  = (float*)(w8 + 29360128);          //    393,216
  ushort* xpeb  = (ushort*)(w8 + 29753344);         //  6,291,456 (bf16)
  ushort* Qb    = (ushort*)(w8 + 36044800);         // 16,777,216 (bf16)
  ushort* Kp    = (ushort*)(w8 + 52822016);         //  8,388,608 (bf16, [b][h][s][dk])
  ushort* Vt    = (ushort*)(w8 + 61210624);         //  8,388,608 (bf16, [b][h][dk][s])
  ushort* Ao    = (ushort*)(w8 + 69599232);         // 16,777,216 (bf16)
  ushort* fcwb  = (ushort*)(w8 + 86376448);         //    131,072 (bf16)
  ushort* xsb   = (ushort*)(w8 + 86507520);         // 16,777,216 (bf16)
  ushort* xvb   = (ushort*)(w8 + 103284736);        //  2,097,152 (bf16)
  ushort* Wgb   = (ushort*)(w8 + 105381888);        //     32,768 (bf16)
  ushort* Wqb   = (ushort*)(w8 + 105414656);        //    131,072 (bf16)
  ushort* Wkb   = (ushort*)(w8 + 105545728);        //     98,304 (bf16)
  ushort* Wvb   = (ushort*)(w8 + 105644032);        //     98,304 (bf16)

  tobf_kernel<<<(B * MN * VD) / 1024, 256, 0, stream>>>(x_velocity, xvb);
  tobf_kernel<<<(B * L * SD) / 1024, 256, 0, stream>>>(x_spatial, xsb);
  tobf_kernel<<<(DM * VD) / 1024, 256, 0, stream>>>(Wg, Wgb);
  tobf_kernel<<<(DM * SD) / 1024, 256, 0, stream>>>(Wq, Wqb);
  tobf_kernel<<<(DM * D3) / 1024, 256, 0, stream>>>(Wk, Wkb);
  tobf_kernel<<<(DM * D3) / 1024, 256, 0, stream>>>(Wv, Wvb);
  tobf_kernel<<<(DM * DM) / 1024, 256, 0, stream>>>(fcw, fcwb);

  msconv_kernel<8><<<B * MN / 8, 192, 0, stream>>>(x_velocity, w3, b3, w5, b5, w7, b7, xm);
  possum_kernel<<<MN, D3, 0, stream>>>(remb, psum);
  pe_kernel<<<B * MN, D3, 0, stream>>>(xm, psum, remb, dww, dwb, xpeb);

  proj_mfma_kernel<VD, 0, 1><<<B * MN / 64, 256, 0, stream>>>(xvb, Wgb, Gamma);
  proj_mfma_kernel<SD, 1, 0><<<B * L / 64, 256, 0, stream>>>(xsb, Wqb, Qb);
  proj_mfma_kernel<D3, 3, 0><<<B * MN / 64, 256, 0, stream>>>(xpeb, Wkb, Kp);
  proj_mfma_kernel<D3, 2, 0><<<B * MN / 64, 256, 0, stream>>>(xpeb, Wvb, Vt);

  attn_mfma_kernel<<<B * NH * (L / 64), 256, 0, stream>>>(Qb, Kp, Vt, Ao);
  final_mfma_kernel<<<B * L / 64, 256, 0, stream>>>(Ao, fcwb, fcb, Gamma,
                                                    x_spatial, lnw, lnb, out);
}